// Round 1
// 805.964 us; speedup vs baseline: 1.0188x; 1.0188x over previous
//
#include <hip/hip_runtime.h>
#include <cstdint>
#include <cstddef>

#define Bx 2
#define Sx 1024
#define Dx 1024
#define Hx 16
#define Lx 4
#define FFx 2048
#define DKx 64
#define Mx (Bx * Sx)   // 2048 rows

typedef __attribute__((ext_vector_type(4))) float f32x4;
typedef __attribute__((ext_vector_type(8))) __bf16 bf16x8;
typedef __attribute__((ext_vector_type(4))) __bf16 bf16x4;
typedef __attribute__((ext_vector_type(2))) __bf16 bf16x2;

// ---------------- embed + positional encoding (pe indexed by BATCH, per ref bug) ----------------
// pair-vectorized: one expf + one sincos per (sin,cos) element pair
__global__ void embed_kernel(const int* __restrict__ tokens,
                             const float* __restrict__ emb,
                             float* __restrict__ x, __bf16* __restrict__ xb) {
  size_t i = (size_t)blockIdx.x * blockDim.x + threadIdx.x;  // over Mx*Dx/2 pairs
  if (i >= (size_t)Mx * Dx / 2) return;
  int p = (int)(i % (Dx / 2));      // pair index within row
  size_t bs = i / (Dx / 2);
  int b = (int)(bs >> 10);          // batch index (Sx = 1024)
  int tok = tokens[bs];
  float arg = (float)b * expf((float)(2 * p) * (-logf(10000.0f) / (float)Dx));
  float sv, cv;
  __sincosf(arg, &sv, &cv);
  const float2 e = ((const float2*)(emb + (size_t)tok * Dx))[p];
  float2 o;
  o.x = e.x + sv;
  o.y = e.y + cv;
  ((float2*)x)[i] = o;
  bf16x2 ob;
  ob[0] = (__bf16)o.x;
  ob[1] = (__bf16)o.y;
  ((bf16x2*)xb)[i] = ob;
}

// ---------------- batched W[K,N] fp32 -> Wt[N,K] bf16 (32x32 tile transpose, z=layer) ----------------
__global__ void transpose_to_bf16(const float* __restrict__ W, __bf16* __restrict__ Wt,
                                  int K, int N, size_t sstride, size_t dstride) {
  __shared__ float tile[32][33];
  const float* Ws = W + blockIdx.z * sstride;
  __bf16* Wd = Wt + blockIdx.z * dstride;
  int tx = threadIdx.x, ty = threadIdx.y;  // 32 x 8
  int n0 = blockIdx.x * 32, k0 = blockIdx.y * 32;
#pragma unroll
  for (int i = 0; i < 4; ++i)
    tile[ty + 8 * i][tx] = Ws[(size_t)(k0 + ty + 8 * i) * N + n0 + tx];
  __syncthreads();
#pragma unroll
  for (int i = 0; i < 4; ++i)
    Wd[(size_t)(n0 + ty + 8 * i) * K + k0 + tx] = (__bf16)tile[tx][ty + 8 * i];
}

// bias concat for all layers: bqkv[L][3072]
__global__ void concat3_kernel(const float* __restrict__ a, const float* __restrict__ b,
                               const float* __restrict__ c, float* __restrict__ out) {
  int i = blockIdx.x * 256 + threadIdx.x;  // over Lx*3072
  int l = i / 3072, j = i % 3072;
  float v = (j < 1024) ? a[l * 1024 + j]
                       : ((j < 2048) ? b[l * 1024 + j - 1024] : c[l * 1024 + j - 2048]);
  out[i] = v;
}

// ---------------- bf16 MFMA GEMM: C = A[M,K] @ Bt[N,K]^T + bias ----------------
// TMxTN tile, BK=32, 4 waves, MI=2/NJ=4 each. Optional split-K via gridDim.z
// (z=1 writes C1, bias only on z=0). Kstep = per-split K; Kld = row stride.
// VOUT: blocks with n0>=2048 are the V projection -> write transposed into VT
// ([b*1024+dk][s] bf16, packed 4-wide) instead of C0; qkvb V region is never
// written (attention reads V only from VT). Replaces the transpose_v kernel.
__device__ __forceinline__ void gld_lds16(const void* g, void* l) {
  __builtin_amdgcn_global_load_lds(
      (const __attribute__((address_space(1))) void*)(uintptr_t)g,
      (__attribute__((address_space(3))) void*)(uintptr_t)l, 16, 0, 0);
}

template <int TM, int TN, bool RELU, typename OutT, bool VOUT = false>
__global__ __launch_bounds__(256) void gemm_bt(const __bf16* __restrict__ A,
                                               const __bf16* __restrict__ Bt,
                                               const float* __restrict__ bias,
                                               OutT* __restrict__ C0,
                                               float* __restrict__ C1,
                                               __bf16* __restrict__ VT,
                                               int Kstep, int Kld, int ldc) {
  static_assert((TM + TN) == 192, "NCH fixed at 12");
  __shared__ __align__(16) __bf16 lds[(TM + TN) * 32];
  const int t = threadIdx.x;
  const int w = t >> 6, lane = t & 63;
  const int quad = lane >> 4, l16 = lane & 15;
  const int m0 = blockIdx.y * TM, n0 = blockIdx.x * TN;
  const int lr = lane >> 2, lc = (lane & 3) * 8;  // staging: row-in-chunk, k-col
  const int koff = blockIdx.z * Kstep;

  f32x4 acc[2][4] = {};

  const int WR = (TN == 128) ? (w >> 1) * (TM / 2) : w * (TM / 4);
  const int WC = (TN == 128) ? (w & 1) * 64 : 0;
  const __bf16* Abase = A + (size_t)m0 * Kld + koff;
  const __bf16* Bbase = Bt + (size_t)n0 * Kld + koff;

  for (int k0 = 0; k0 < Kstep; k0 += 32) {
    __syncthreads();
#pragma unroll
    for (int c = 0; c < 3; ++c) {
      const int ch = c * 4 + w;
      const int r = ch * 16 + lr;
      const __bf16* g = (r < TM) ? (Abase + (size_t)r * Kld + k0 + lc)
                                 : (Bbase + (size_t)(r - TM) * Kld + k0 + lc);
      gld_lds16(g, (void*)(lds + ch * 512));
    }
    __syncthreads();
    bf16x8 af[2], bfr[4];
#pragma unroll
    for (int i = 0; i < 2; ++i)
      af[i] = *(const bf16x8*)&lds[(WR + i * 16 + l16) * 32 + quad * 8];
#pragma unroll
    for (int j = 0; j < 4; ++j)
      bfr[j] = *(const bf16x8*)&lds[(TM + WC + j * 16 + l16) * 32 + quad * 8];
#pragma unroll
    for (int i = 0; i < 2; ++i)
#pragma unroll
      for (int j = 0; j < 4; ++j)
        acc[i][j] = __builtin_amdgcn_mfma_f32_16x16x32_bf16(af[i], bfr[j], acc[i][j], 0, 0, 0);
  }

  // epilogue: C/D layout col=lane&15, row=(lane>>4)*4+reg (m89/m91-verified)
  const int col0 = n0 + WC + l16;

  if (VOUT && n0 >= 2048) {
    // V projection block: write transposed into VT. Row = b*1024 + dk (dk = n-2048),
    // col = s = m & 1023 (m0 is 128-aligned so the whole block shares b = m0>>10).
    const int b = m0 >> 10;
    const int sbase = (m0 & 1023) + WR;
#pragma unroll
    for (int j = 0; j < 4; ++j) {
      const int n = col0 + j * 16;
      const int dk = n - 2048;
      const float bn = bias[n];
      __bf16* vrow = VT + (size_t)(b * 1024 + dk) * Sx + sbase;
#pragma unroll
      for (int i = 0; i < 2; ++i) {
        bf16x4 pk;
#pragma unroll
        for (int r = 0; r < 4; ++r) pk[r] = (__bf16)(acc[i][j][r] + bn);
        *(bf16x4*)(vrow + i * 16 + quad * 4) = pk;
      }
    }
    return;
  }

  const bool z0 = (blockIdx.z == 0);
#pragma unroll
  for (int j = 0; j < 4; ++j) {
    const int n = col0 + j * 16;
    const float bn = z0 ? bias[n] : 0.f;
#pragma unroll
    for (int i = 0; i < 2; ++i) {
#pragma unroll
      for (int r = 0; r < 4; ++r) {
        const int m = m0 + WR + i * 16 + quad * 4 + r;
        float v = acc[i][j][r] + bn;
        if (RELU) v = fmaxf(v, 0.f);
        if (z0)
          C0[(size_t)m * ldc + n] = (OutT)v;
        else
          C1[(size_t)m * ldc + n] = v;
      }
    }
  }
}

// ---------------- MFMA flash attention: padded double-buffered LDS staging ----------------
// grid (S/64, H, B), 256 threads (4 waves x 16 queries). One barrier per K-tile;
// tile kt+1 global loads prefetched into regs during tile kt compute.
// Softmax without max-subtraction (scores bounded), exp2 w/ folded scale,
// l-reduction deferred to epilogue.
__global__ __launch_bounds__(256) void attention_mfma(const __bf16* __restrict__ QKV,
                                                      const __bf16* __restrict__ Vt,
                                                      __bf16* __restrict__ O) {
  __shared__ __align__(16) __bf16 Ks[2][64 * 72];  // [key][dk], stride 72 (bank-uniform)
  __shared__ __align__(16) __bf16 Vs[2][64 * 72];  // [dk][key], stride 72
  __shared__ __align__(16) __bf16 Pl[64 * 72];     // wave-private rows: [q][key]

  const int t = threadIdx.x;
  const int w = t >> 6, lane = t & 63;
  const int quad = lane >> 4, l16 = lane & 15;
  const int q0 = blockIdx.x * 64;
  const int h = blockIdx.y, b = blockIdx.z;
  const size_t rowbase = (size_t)b * Sx;
  const int hoff = h * 64;

  // Q fragments: A[m=l16][k=quad*8+j], in registers for the whole kernel
  const __bf16* qrow = QKV + (rowbase + q0 + w * 16 + l16) * 3072 + hoff;
  bf16x8 qf0 = *(const bf16x8*)(qrow + quad * 8);
  bf16x8 qf1 = *(const bf16x8*)(qrow + 32 + quad * 8);

  const __bf16* Kbase = QKV + rowbase * 3072 + 1024 + hoff;
  const __bf16* Vbase = Vt + (size_t)(b * Hx + h) * 64 * Sx;

  // staging role: thread t covers row srow, 32B segment sseg (coalesced 128B/4 lanes)
  const int srow = t >> 2, sseg = t & 3;
  bf16x8 kp0, kp1, vp0, vp1;

  f32x4 oacc[4] = {};
  f32x4 lacc = {0.f, 0.f, 0.f, 0.f};
  const float cs = 0.125f * 1.44269504089f;  // fold 1/sqrt(64) and log2(e)

  // prologue: stage tile 0
  {
    const __bf16* kr = Kbase + (size_t)srow * 3072 + sseg * 16;
    kp0 = *(const bf16x8*)kr;
    kp1 = *(const bf16x8*)(kr + 8);
    const __bf16* vr = Vbase + (size_t)srow * Sx + sseg * 16;
    vp0 = *(const bf16x8*)vr;
    vp1 = *(const bf16x8*)(vr + 8);
    *(bf16x8*)&Ks[0][srow * 72 + sseg * 16] = kp0;
    *(bf16x8*)&Ks[0][srow * 72 + sseg * 16 + 8] = kp1;
    *(bf16x8*)&Vs[0][srow * 72 + sseg * 16] = vp0;
    *(bf16x8*)&Vs[0][srow * 72 + sseg * 16 + 8] = vp1;
  }
  __syncthreads();

  for (int kt = 0; kt < Sx / 64; ++kt) {
    const int cur = kt & 1;
    // prefetch next tile into regs (lands during this tile's compute)
    if (kt < Sx / 64 - 1) {
      const int kn = (kt + 1) * 64;
      const __bf16* kr = Kbase + (size_t)(kn + srow) * 3072 + sseg * 16;
      kp0 = *(const bf16x8*)kr;
      kp1 = *(const bf16x8*)(kr + 8);
      const __bf16* vr = Vbase + (size_t)srow * Sx + kn + sseg * 16;
      vp0 = *(const bf16x8*)vr;
      vp1 = *(const bf16x8*)(vr + 8);
    }

    // QK^T: B-fragments from padded LDS
    f32x4 s[4] = {};
#pragma unroll
    for (int j = 0; j < 4; ++j) {
      bf16x8 b0 = *(const bf16x8*)&Ks[cur][(j * 16 + l16) * 72 + quad * 8];
      bf16x8 b1 = *(const bf16x8*)&Ks[cur][(j * 16 + l16) * 72 + 32 + quad * 8];
      s[j] = __builtin_amdgcn_mfma_f32_16x16x32_bf16(qf0, b0, s[j], 0, 0, 0);
      s[j] = __builtin_amdgcn_mfma_f32_16x16x32_bf16(qf1, b1, s[j], 0, 0, 0);
    }

    // p = exp2(s*cs); accumulate per-lane partial row sums
#pragma unroll
    for (int j = 0; j < 4; ++j) {
#pragma unroll
      for (int r = 0; r < 4; ++r) s[j][r] = __builtin_exp2f(s[j][r] * cs);
      lacc += s[j];
    }

    // P: C-layout -> wave-private LDS rows (no barrier; DS in-order per wave)
#pragma unroll
    for (int r = 0; r < 4; ++r) {
      const int prow = (w * 16 + quad * 4 + r) * 72;
#pragma unroll
      for (int j = 0; j < 4; ++j) Pl[prow + j * 16 + l16] = (__bf16)s[j][r];
    }
    bf16x8 pa0 = *(const bf16x8*)&Pl[(w * 16 + l16) * 72 + quad * 8];
    bf16x8 pa1 = *(const bf16x8*)&Pl[(w * 16 + l16) * 72 + 32 + quad * 8];

    // PV: B-fragments from padded LDS
#pragma unroll
    for (int j = 0; j < 4; ++j) {
      bf16x8 vb0 = *(const bf16x8*)&Vs[cur][(j * 16 + l16) * 72 + quad * 8];
      bf16x8 vb1 = *(const bf16x8*)&Vs[cur][(j * 16 + l16) * 72 + 32 + quad * 8];
      oacc[j] = __builtin_amdgcn_mfma_f32_16x16x32_bf16(pa0, vb0, oacc[j], 0, 0, 0);
      oacc[j] = __builtin_amdgcn_mfma_f32_16x16x32_bf16(pa1, vb1, oacc[j], 0, 0, 0);
    }

    // write prefetched tile into the other buffer (its readers synced last barrier)
    if (kt < Sx / 64 - 1) {
      const int nxt = 1 - cur;
      *(bf16x8*)&Ks[nxt][srow * 72 + sseg * 16] = kp0;
      *(bf16x8*)&Ks[nxt][srow * 72 + sseg * 16 + 8] = kp1;
      *(bf16x8*)&Vs[nxt][srow * 72 + sseg * 16] = vp0;
      *(bf16x8*)&Vs[nxt][srow * 72 + sseg * 16 + 8] = vp1;
    }
    __syncthreads();
  }

  // epilogue: reduce l across the 16-lane column group, divide, write bf16
#pragma unroll
  for (int r = 0; r < 4; ++r) {
    float lr = lacc[r];
    lr += __shfl_xor(lr, 1);
    lr += __shfl_xor(lr, 2);
    lr += __shfl_xor(lr, 4);
    lr += __shfl_xor(lr, 8);
    const float inv = 1.f / lr;
    const size_t orow = (rowbase + q0 + w * 16 + quad * 4 + r) * 1024 + hoff;
#pragma unroll
    for (int j = 0; j < 4; ++j) O[orow + j * 16 + l16] = (__bf16)(oacc[j][r] * inv);
  }
}

// ---------------- fused residual add (x + r0 + r1) + LayerNorm, dual fp32+bf16 out ----------------
// wave-shuffle reductions (2 barriers total), f32x4 vectorized loads/stores
__global__ void add_ln_kernel(const float* __restrict__ x, const float* __restrict__ r0,
                              const float* __restrict__ r1,
                              const float* __restrict__ gamma, const float* __restrict__ beta,
                              float* __restrict__ out, __bf16* __restrict__ outb) {
  const int row = blockIdx.x, t = threadIdx.x;
  const int lane = t & 63, w = t >> 6;
  __shared__ float red[2][4];
  const f32x4* xr = (const f32x4*)(x + (size_t)row * Dx);
  const f32x4* a0 = (const f32x4*)(r0 + (size_t)row * Dx);
  const f32x4* a1 = (const f32x4*)(r1 + (size_t)row * Dx);
  f32x4 v = xr[t] + a0[t] + a1[t];
  float s = v[0] + v[1] + v[2] + v[3];
#pragma unroll
  for (int off = 1; off < 64; off <<= 1) s += __shfl_xor(s, off);
  if (lane == 0) red[0][w] = s;
  __syncthreads();
  const float mu = (red[0][0] + red[0][1] + red[0][2] + red[0][3]) * (1.f / Dx);
  f32x4 d = v - mu;
  float vs = d[0] * d[0] + d[1] * d[1] + d[2] * d[2] + d[3] * d[3];
#pragma unroll
  for (int off = 1; off < 64; off <<= 1) vs += __shfl_xor(vs, off);
  if (lane == 0) red[1][w] = vs;
  __syncthreads();
  const float is = rsqrtf((red[1][0] + red[1][1] + red[1][2] + red[1][3]) * (1.f / Dx) + 1e-5f);
  f32x4 g = ((const f32x4*)gamma)[t];
  f32x4 be = ((const f32x4*)beta)[t];
  f32x4 y = d * is * g + be;
  ((f32x4*)(out + (size_t)row * Dx))[t] = y;
  bf16x4 yb;
#pragma unroll
  for (int r = 0; r < 4; ++r) yb[r] = (__bf16)y[r];
  ((bf16x4*)(outb + (size_t)row * Dx))[t] = yb;
}

extern "C" void kernel_launch(void* const* d_in, const int* in_sizes, int n_in,
                              void* d_out, int out_size, void* d_ws, size_t ws_size,
                              hipStream_t stream) {
  const int* tokens = (const int*)d_in[0];
  const float* emb = (const float*)d_in[1];
  const float* Wq = (const float*)d_in[2];
  const float* bq = (const float*)d_in[3];
  const float* Wk = (const float*)d_in[4];
  const float* bk = (const float*)d_in[5];
  const float* Wv = (const float*)d_in[6];
  const float* bv = (const float*)d_in[7];
  const float* Wo = (const float*)d_in[8];
  const float* bo = (const float*)d_in[9];
  const float* W1 = (const float*)d_in[10];
  const float* b1 = (const float*)d_in[11];
  const float* W2 = (const float*)d_in[12];
  const float* b2 = (const float*)d_in[13];
  const float* gamma = (const float*)d_in[14];
  const float* beta = (const float*)d_in[15];

  const size_t M1 = 1024 * 1024;
  float* ws = (float*)d_ws;
  float* x = ws;                        // 2M f32
  float* tmp = ws + 2 * M1;             // 2M f32 (split-K partial 0)
  __bf16* bfr = (__bf16*)(ws + 4 * M1);
  __bf16* xb = bfr;                     // 2M
  __bf16* qkvb = bfr + 2 * M1;          // 6M  [2048][3072] (V cols unused)
  __bf16* ob = bfr + 8 * M1;            // 2M
  __bf16* h1b = bfr + 10 * M1;          // 4M  [2048][2048]
  __bf16* Vt = bfr + 14 * M1;           // 2M  [B*H*64][S]
  __bf16* WqkvT = bfr + 16 * M1;        // 12M [L][3072][1024]
  __bf16* WoT = bfr + 28 * M1;          // 4M  [L][1024][1024]
  __bf16* W1T = bfr + 32 * M1;          // 8M  [L][2048][1024]
  __bf16* W2T = bfr + 40 * M1;          // 8M  [L][1024][2048]
  float* bqkv = (float*)(bfr + 48 * M1);  // [L][3072] f32
  float* tmp1 = (float*)qkvb;           // split-K partial 1 (qkvb free during Wo/FF2)

  embed_kernel<<<((size_t)Mx * Dx / 2 + 255) / 256, 256, 0, stream>>>(tokens, emb, x, xb);

  // batched weight prep for ALL layers (7 launches total)
  dim3 tb(32, 8);
  transpose_to_bf16<<<dim3(32, 32, Lx), tb, 0, stream>>>(Wq, WqkvT, Dx, Dx, M1, 3 * M1);
  transpose_to_bf16<<<dim3(32, 32, Lx), tb, 0, stream>>>(Wk, WqkvT + M1, Dx, Dx, M1, 3 * M1);
  transpose_to_bf16<<<dim3(32, 32, Lx), tb, 0, stream>>>(Wv, WqkvT + 2 * M1, Dx, Dx, M1, 3 * M1);
  transpose_to_bf16<<<dim3(32, 32, Lx), tb, 0, stream>>>(Wo, WoT, Dx, Dx, M1, M1);
  transpose_to_bf16<<<dim3(64, 32, Lx), tb, 0, stream>>>(W1, W1T, Dx, FFx, 2 * M1, 2 * M1);
  transpose_to_bf16<<<dim3(32, 64, Lx), tb, 0, stream>>>(W2, W2T, FFx, Dx, 2 * M1, 2 * M1);
  concat3_kernel<<<Lx * 12, 256, 0, stream>>>(bq, bk, bv, bqkv);

  for (int l = 0; l < Lx; ++l) {
    const __bf16* WqkvT_l = WqkvT + (size_t)l * 3 * M1;
    const __bf16* WoT_l = WoT + (size_t)l * M1;
    const __bf16* W1T_l = W1T + (size_t)l * 2 * M1;
    const __bf16* W2T_l = W2T + (size_t)l * 2 * M1;
    const float* bqkv_l = bqkv + (size_t)l * 3072;
    const float* bo_l = bo + (size_t)l * Dx;
    const float* b1_l = b1 + (size_t)l * FFx;
    const float* b2_l = b2 + (size_t)l * Dx;
    const float* g_l = gamma + (size_t)l * Dx;
    const float* be_l = beta + (size_t)l * Dx;

    // QKV: 128x64 tiles -> 768 blocks (3/CU); V blocks write transposed into Vt
    gemm_bt<128, 64, false, __bf16, true><<<dim3(3072 / 64, Mx / 128, 1), 256, 0, stream>>>(
        xb, WqkvT_l, bqkv_l, qkvb, nullptr, Vt, Dx, Dx, 3072);

    attention_mfma<<<dim3(Sx / 64, Hx, Bx), 256, 0, stream>>>(qkvb, Vt, ob);

    // Wo: 64x128 tiles, split-K=2 -> 512 blocks (2/CU); partials in tmp/tmp1
    gemm_bt<64, 128, false, float><<<dim3(Dx / 128, Mx / 64, 2), 256, 0, stream>>>(
        ob, WoT_l, bo_l, tmp, tmp1, nullptr, Dx / 2, Dx, Dx);
    add_ln_kernel<<<Mx, 256, 0, stream>>>(x, tmp, tmp1, g_l, be_l, x, xb);

    // FF1: 128x64 tiles -> 512 blocks (2/CU)
    gemm_bt<128, 64, true, __bf16><<<dim3(FFx / 64, Mx / 128, 1), 256, 0, stream>>>(
        xb, W1T_l, b1_l, h1b, nullptr, nullptr, Dx, Dx, FFx);
    // FF2: 64x128 tiles, split-K=2 -> 512 blocks
    gemm_bt<64, 128, false, float><<<dim3(Dx / 128, Mx / 64, 2), 256, 0, stream>>>(
        h1b, W2T_l, b2_l, tmp, tmp1, nullptr, FFx / 2, FFx, Dx);
    add_ln_kernel<<<Mx, 256, 0, stream>>>(x, tmp, tmp1, g_l, be_l,
                                          (l == Lx - 1) ? (float*)d_out : x, xb);
  }
}

// Round 2
// 793.266 us; speedup vs baseline: 1.0351x; 1.0160x over previous
//
#include <hip/hip_runtime.h>
#include <cstdint>
#include <cstddef>

#define Bx 2
#define Sx 1024
#define Dx 1024
#define Hx 16
#define Lx 4
#define FFx 2048
#define DKx 64
#define Mx (Bx * Sx)   // 2048 rows

typedef __attribute__((ext_vector_type(4))) float f32x4;
typedef __attribute__((ext_vector_type(8))) __bf16 bf16x8;
typedef __attribute__((ext_vector_type(4))) __bf16 bf16x4;
typedef __attribute__((ext_vector_type(2))) __bf16 bf16x2;

// ---------------- embed + positional encoding (pe indexed by BATCH, per ref bug) ----------------
__global__ void embed_kernel(const int* __restrict__ tokens,
                             const float* __restrict__ emb,
                             float* __restrict__ x, __bf16* __restrict__ xb) {
  size_t i = (size_t)blockIdx.x * blockDim.x + threadIdx.x;  // over Mx*Dx/2 pairs
  if (i >= (size_t)Mx * Dx / 2) return;
  int p = (int)(i % (Dx / 2));      // pair index within row
  size_t bs = i / (Dx / 2);
  int b = (int)(bs >> 10);          // batch index (Sx = 1024)
  int tok = tokens[bs];
  float arg = (float)b * expf((float)(2 * p) * (-logf(10000.0f) / (float)Dx));
  float sv, cv;
  __sincosf(arg, &sv, &cv);
  const float2 e = ((const float2*)(emb + (size_t)tok * Dx))[p];
  float2 o;
  o.x = e.x + sv;
  o.y = e.y + cv;
  ((float2*)x)[i] = o;
  bf16x2 ob;
  ob[0] = (__bf16)o.x;
  ob[1] = (__bf16)o.y;
  ((bf16x2*)xb)[i] = ob;
}

// ---------------- batched W[K,N] fp32 -> Wt[N,K] bf16 (32x32 tile transpose, z=layer) ----------------
__global__ void transpose_to_bf16(const float* __restrict__ W, __bf16* __restrict__ Wt,
                                  int K, int N, size_t sstride, size_t dstride) {
  __shared__ float tile[32][33];
  const float* Ws = W + blockIdx.z * sstride;
  __bf16* Wd = Wt + blockIdx.z * dstride;
  int tx = threadIdx.x, ty = threadIdx.y;  // 32 x 8
  int n0 = blockIdx.x * 32, k0 = blockIdx.y * 32;
#pragma unroll
  for (int i = 0; i < 4; ++i)
    tile[ty + 8 * i][tx] = Ws[(size_t)(k0 + ty + 8 * i) * N + n0 + tx];
  __syncthreads();
#pragma unroll
  for (int i = 0; i < 4; ++i)
    Wd[(size_t)(n0 + ty + 8 * i) * K + k0 + tx] = (__bf16)tile[tx][ty + 8 * i];
}

// 4 DxD weight transposes (Wq,Wk,Wv,Wo for all layers) in ONE launch: z = l*4 + which
struct T4Args {
  const float* s0; const float* s1; const float* s2; const float* s3;
  __bf16* d0; __bf16* d1; __bf16* d2; __bf16* d3;
};
__global__ void transpose4_to_bf16(T4Args a) {
  __shared__ float tile[32][33];
  const int zz = blockIdx.z, l = zz >> 2, which = zz & 3;
  const size_t M1c = (size_t)Dx * Dx;
  const float* Ws = (which == 0 ? a.s0 : which == 1 ? a.s1 : which == 2 ? a.s2 : a.s3) + (size_t)l * M1c;
  __bf16* Wd = (which == 0)   ? a.d0 + (size_t)l * 3 * M1c
               : (which == 1) ? a.d1 + (size_t)l * 3 * M1c
               : (which == 2) ? a.d2 + (size_t)l * 3 * M1c
                              : a.d3 + (size_t)l * M1c;
  int tx = threadIdx.x, ty = threadIdx.y;  // 32 x 8
  int n0 = blockIdx.x * 32, k0 = blockIdx.y * 32;
#pragma unroll
  for (int i = 0; i < 4; ++i)
    tile[ty + 8 * i][tx] = Ws[(size_t)(k0 + ty + 8 * i) * Dx + n0 + tx];
  __syncthreads();
#pragma unroll
  for (int i = 0; i < 4; ++i)
    Wd[(size_t)(n0 + ty + 8 * i) * Dx + k0 + tx] = (__bf16)tile[tx][ty + 8 * i];
}

// bias concat for all layers: bqkv[L][3072]
__global__ void concat3_kernel(const float* __restrict__ a, const float* __restrict__ b,
                               const float* __restrict__ c, float* __restrict__ out) {
  int i = blockIdx.x * 256 + threadIdx.x;  // over Lx*3072
  int l = i / 3072, j = i % 3072;
  float v = (j < 1024) ? a[l * 1024 + j]
                       : ((j < 2048) ? b[l * 1024 + j - 1024] : c[l * 1024 + j - 2048]);
  out[i] = v;
}

// ---------------- bf16 MFMA GEMM: C = A[M,K] @ Bt[N,K]^T + bias ----------------
// TMxTN tile, BK=32, 4 waves, MI=2/NJ=4 each. Optional split-K via gridDim.z
// (z=1 writes C1, bias only on z=0). Kstep = per-split K; Kld = row stride.
// VOUT: blocks with n0>=2048 are the V projection -> LDS-transpose the tile and
// write coalesced 64B segments into VT ([b*1024+dk][s] bf16). qkvb V region is
// never written (attention reads V only from VT).
__device__ __forceinline__ void gld_lds16(const void* g, void* l) {
  __builtin_amdgcn_global_load_lds(
      (const __attribute__((address_space(1))) void*)(uintptr_t)g,
      (__attribute__((address_space(3))) void*)(uintptr_t)l, 16, 0, 0);
}

template <int TM, int TN, bool RELU, typename OutT, bool VOUT = false>
__global__ __launch_bounds__(256) void gemm_bt(const __bf16* __restrict__ A,
                                               const __bf16* __restrict__ Bt,
                                               const float* __restrict__ bias,
                                               OutT* __restrict__ C0,
                                               float* __restrict__ C1,
                                               __bf16* __restrict__ VT,
                                               int Kstep, int Kld, int ldc) {
  static_assert((TM + TN) == 192, "NCH fixed at 12");
  static_assert(!VOUT || TN == 64, "VOUT path assumes TN=64/WC=0");
  constexpr int LDSE = VOUT ? 64 * 136 : (TM + TN) * 32;  // VOUT: reuse as 64x136 transpose tile
  __shared__ __align__(16) __bf16 lds[LDSE];
  const int t = threadIdx.x;
  const int w = t >> 6, lane = t & 63;
  const int quad = lane >> 4, l16 = lane & 15;
  const int m0 = blockIdx.y * TM, n0 = blockIdx.x * TN;
  const int lr = lane >> 2, lc = (lane & 3) * 8;  // staging: row-in-chunk, k-col
  const int koff = blockIdx.z * Kstep;

  f32x4 acc[2][4] = {};

  const int WR = (TN == 128) ? (w >> 1) * (TM / 2) : w * (TM / 4);
  const int WC = (TN == 128) ? (w & 1) * 64 : 0;
  const __bf16* Abase = A + (size_t)m0 * Kld + koff;
  const __bf16* Bbase = Bt + (size_t)n0 * Kld + koff;

  for (int k0 = 0; k0 < Kstep; k0 += 32) {
    __syncthreads();
#pragma unroll
    for (int c = 0; c < 3; ++c) {
      const int ch = c * 4 + w;
      const int r = ch * 16 + lr;
      const __bf16* g = (r < TM) ? (Abase + (size_t)r * Kld + k0 + lc)
                                 : (Bbase + (size_t)(r - TM) * Kld + k0 + lc);
      gld_lds16(g, (void*)(lds + ch * 512));
    }
    __syncthreads();
    bf16x8 af[2], bfr[4];
#pragma unroll
    for (int i = 0; i < 2; ++i)
      af[i] = *(const bf16x8*)&lds[(WR + i * 16 + l16) * 32 + quad * 8];
#pragma unroll
    for (int j = 0; j < 4; ++j)
      bfr[j] = *(const bf16x8*)&lds[(TM + WC + j * 16 + l16) * 32 + quad * 8];
#pragma unroll
    for (int i = 0; i < 2; ++i)
#pragma unroll
      for (int j = 0; j < 4; ++j)
        acc[i][j] = __builtin_amdgcn_mfma_f32_16x16x32_bf16(af[i], bfr[j], acc[i][j], 0, 0, 0);
  }

  // epilogue: C/D layout col=lane&15, row=(lane>>4)*4+reg (m89/m91-verified)
  const int col0 = n0 + WC + l16;

  if (VOUT && n0 >= 2048) {
    // V projection block: transpose through LDS, then coalesced stores into VT.
    __syncthreads();  // all waves done reading staging LDS
#pragma unroll
    for (int j = 0; j < 4; ++j) {
      const float bn = bias[col0 + j * 16];
      const int nl = (l16 + j * 16) * 136;  // dk-local row, padded stride (68 dw = 4 mod 32)
#pragma unroll
      for (int i = 0; i < 2; ++i)
#pragma unroll
        for (int r = 0; r < 4; ++r)
          lds[nl + WR + i * 16 + quad * 4 + r] = (__bf16)(acc[i][j][r] + bn);
    }
    __syncthreads();
    const int b = m0 >> 10;
    const int sbase = m0 & 1023;
    const int row = t >> 2, seg = t & 3;  // 64 rows x 4 segs of 64B
    __bf16* vrow = VT + (size_t)(b * 1024 + (n0 - 2048) + row) * Sx + sbase + seg * 32;
    const __bf16* lrow = lds + row * 136 + seg * 32;
#pragma unroll
    for (int q = 0; q < 4; ++q)
      *(bf16x8*)(vrow + q * 8) = *(const bf16x8*)(lrow + q * 8);
    return;
  }

  const bool z0 = (blockIdx.z == 0);
#pragma unroll
  for (int j = 0; j < 4; ++j) {
    const int n = col0 + j * 16;
    const float bn = z0 ? bias[n] : 0.f;
#pragma unroll
    for (int i = 0; i < 2; ++i) {
#pragma unroll
      for (int r = 0; r < 4; ++r) {
        const int m = m0 + WR + i * 16 + quad * 4 + r;
        float v = acc[i][j][r] + bn;
        if (RELU) v = fmaxf(v, 0.f);
        if (z0)
          C0[(size_t)m * ldc + n] = (OutT)v;
        else
          C1[(size_t)m * ldc + n] = v;
      }
    }
  }
}

// ---------------- MFMA flash attention: swapped QK^T, padded double-buffered LDS ----------------
// grid (S/64, H, B), 256 threads (4 waves x 16 queries). One barrier per K-tile.
// QK^T computed as mfma(K,Q) so each lane holds P[q=w*16+l16][keys j*16+quad*4+r]:
// P->LDS is 4x ds_write_b64 (packed keys), l-sum is a single scalar per lane.
__global__ __launch_bounds__(256) void attention_mfma(const __bf16* __restrict__ QKV,
                                                      const __bf16* __restrict__ Vt,
                                                      __bf16* __restrict__ O) {
  __shared__ __align__(16) __bf16 Ks[2][64 * 72];  // [key][dk], stride 72
  __shared__ __align__(16) __bf16 Vs[2][64 * 72];  // [dk][key], stride 72
  __shared__ __align__(16) __bf16 Pl[64 * 72];     // wave-private rows: [q][key]

  const int t = threadIdx.x;
  const int w = t >> 6, lane = t & 63;
  const int quad = lane >> 4, l16 = lane & 15;
  const int q0 = blockIdx.x * 64;
  const int h = blockIdx.y, b = blockIdx.z;
  const size_t rowbase = (size_t)b * Sx;
  const int hoff = h * 64;

  // Q fragments: rows q=w*16+l16, k=quad*8+e, in registers for the whole kernel
  const __bf16* qrow = QKV + (rowbase + q0 + w * 16 + l16) * 3072 + hoff;
  bf16x8 qf0 = *(const bf16x8*)(qrow + quad * 8);
  bf16x8 qf1 = *(const bf16x8*)(qrow + 32 + quad * 8);

  const __bf16* Kbase = QKV + rowbase * 3072 + 1024 + hoff;
  const __bf16* Vbase = Vt + (size_t)(b * Hx + h) * 64 * Sx;

  // staging role: thread t covers row srow, 32B segment sseg (coalesced 128B/4 lanes)
  const int srow = t >> 2, sseg = t & 3;
  bf16x8 kp0, kp1, vp0, vp1;

  f32x4 oacc[4] = {};
  float lsum = 0.f;
  const float cs = 0.125f * 1.44269504089f;  // fold 1/sqrt(64) and log2(e)

  // prologue: stage tile 0
  {
    const __bf16* kr = Kbase + (size_t)srow * 3072 + sseg * 16;
    kp0 = *(const bf16x8*)kr;
    kp1 = *(const bf16x8*)(kr + 8);
    const __bf16* vr = Vbase + (size_t)srow * Sx + sseg * 16;
    vp0 = *(const bf16x8*)vr;
    vp1 = *(const bf16x8*)(vr + 8);
    *(bf16x8*)&Ks[0][srow * 72 + sseg * 16] = kp0;
    *(bf16x8*)&Ks[0][srow * 72 + sseg * 16 + 8] = kp1;
    *(bf16x8*)&Vs[0][srow * 72 + sseg * 16] = vp0;
    *(bf16x8*)&Vs[0][srow * 72 + sseg * 16 + 8] = vp1;
  }
  __syncthreads();

  for (int kt = 0; kt < Sx / 64; ++kt) {
    const int cur = kt & 1;
    // prefetch next tile into regs (lands during this tile's compute)
    if (kt < Sx / 64 - 1) {
      const int kn = (kt + 1) * 64;
      const __bf16* kr = Kbase + (size_t)(kn + srow) * 3072 + sseg * 16;
      kp0 = *(const bf16x8*)kr;
      kp1 = *(const bf16x8*)(kr + 8);
      const __bf16* vr = Vbase + (size_t)srow * Sx + kn + sseg * 16;
      vp0 = *(const bf16x8*)vr;
      vp1 = *(const bf16x8*)(vr + 8);
    }

    // QK^T swapped: A=K-frag, B=Q-frag -> D[key][q]; lane holds q=w*16+l16,
    // keys j*16+quad*4+r
    f32x4 s[4] = {};
#pragma unroll
    for (int j = 0; j < 4; ++j) {
      bf16x8 b0 = *(const bf16x8*)&Ks[cur][(j * 16 + l16) * 72 + quad * 8];
      bf16x8 b1 = *(const bf16x8*)&Ks[cur][(j * 16 + l16) * 72 + 32 + quad * 8];
      s[j] = __builtin_amdgcn_mfma_f32_16x16x32_bf16(b0, qf0, s[j], 0, 0, 0);
      s[j] = __builtin_amdgcn_mfma_f32_16x16x32_bf16(b1, qf1, s[j], 0, 0, 0);
    }

    // p = exp2(s*cs); accumulate scalar row-sum (this lane's q only)
#pragma unroll
    for (int j = 0; j < 4; ++j) {
#pragma unroll
      for (int r = 0; r < 4; ++r) s[j][r] = __builtin_exp2f(s[j][r] * cs);
      lsum += s[j][0] + s[j][1] + s[j][2] + s[j][3];
    }

    // P -> wave-private LDS rows: 4x packed b64 (keys j*16+quad*4..+3)
    const int prow = (w * 16 + l16) * 72;
#pragma unroll
    for (int j = 0; j < 4; ++j) {
      bf16x4 pk;
#pragma unroll
      for (int r = 0; r < 4; ++r) pk[r] = (__bf16)s[j][r];
      *(bf16x4*)&Pl[prow + j * 16 + quad * 4] = pk;
    }
    bf16x8 pa0 = *(const bf16x8*)&Pl[prow + quad * 8];
    bf16x8 pa1 = *(const bf16x8*)&Pl[prow + 32 + quad * 8];

    // PV: B-fragments from padded LDS
#pragma unroll
    for (int j = 0; j < 4; ++j) {
      bf16x8 vb0 = *(const bf16x8*)&Vs[cur][(j * 16 + l16) * 72 + quad * 8];
      bf16x8 vb1 = *(const bf16x8*)&Vs[cur][(j * 16 + l16) * 72 + 32 + quad * 8];
      oacc[j] = __builtin_amdgcn_mfma_f32_16x16x32_bf16(pa0, vb0, oacc[j], 0, 0, 0);
      oacc[j] = __builtin_amdgcn_mfma_f32_16x16x32_bf16(pa1, vb1, oacc[j], 0, 0, 0);
    }

    // write prefetched tile into the other buffer (its readers synced last barrier)
    if (kt < Sx / 64 - 1) {
      const int nxt = 1 - cur;
      *(bf16x8*)&Ks[nxt][srow * 72 + sseg * 16] = kp0;
      *(bf16x8*)&Ks[nxt][srow * 72 + sseg * 16 + 8] = kp1;
      *(bf16x8*)&Vs[nxt][srow * 72 + sseg * 16] = vp0;
      *(bf16x8*)&Vs[nxt][srow * 72 + sseg * 16 + 8] = vp1;
    }
    __syncthreads();
  }

  // epilogue: lsum holds partial over this lane's quad; full sum = reduce over quads
  lsum += __shfl_xor(lsum, 16);
  lsum += __shfl_xor(lsum, 32);
  const float inv = 1.f / lsum;  // valid for q = w*16 + l16
#pragma unroll
  for (int r = 0; r < 4; ++r) {
    const float invr = __shfl(inv, quad * 4 + r);  // lane l16'=quad*4+r holds that q's inv
    const size_t orow = (rowbase + q0 + w * 16 + quad * 4 + r) * 1024 + hoff;
#pragma unroll
    for (int j = 0; j < 4; ++j) O[orow + j * 16 + l16] = (__bf16)(oacc[j][r] * invr);
  }
}

// ---------------- fused residual add (x + r0 + r1) + LayerNorm, dual fp32+bf16 out ----------------
__global__ void add_ln_kernel(const float* __restrict__ x, const float* __restrict__ r0,
                              const float* __restrict__ r1,
                              const float* __restrict__ gamma, const float* __restrict__ beta,
                              float* __restrict__ out, __bf16* __restrict__ outb) {
  const int row = blockIdx.x, t = threadIdx.x;
  const int lane = t & 63, w = t >> 6;
  __shared__ float red[2][4];
  const f32x4* xr = (const f32x4*)(x + (size_t)row * Dx);
  const f32x4* a0 = (const f32x4*)(r0 + (size_t)row * Dx);
  const f32x4* a1 = (const f32x4*)(r1 + (size_t)row * Dx);
  f32x4 v = xr[t] + a0[t] + a1[t];
  float s = v[0] + v[1] + v[2] + v[3];
#pragma unroll
  for (int off = 1; off < 64; off <<= 1) s += __shfl_xor(s, off);
  if (lane == 0) red[0][w] = s;
  __syncthreads();
  const float mu = (red[0][0] + red[0][1] + red[0][2] + red[0][3]) * (1.f / Dx);
  f32x4 d = v - mu;
  float vs = d[0] * d[0] + d[1] * d[1] + d[2] * d[2] + d[3] * d[3];
#pragma unroll
  for (int off = 1; off < 64; off <<= 1) vs += __shfl_xor(vs, off);
  if (lane == 0) red[1][w] = vs;
  __syncthreads();
  const float is = rsqrtf((red[1][0] + red[1][1] + red[1][2] + red[1][3]) * (1.f / Dx) + 1e-5f);
  f32x4 g = ((const f32x4*)gamma)[t];
  f32x4 be = ((const f32x4*)beta)[t];
  f32x4 y = d * is * g + be;
  ((f32x4*)(out + (size_t)row * Dx))[t] = y;
  bf16x4 yb;
#pragma unroll
  for (int r = 0; r < 4; ++r) yb[r] = (__bf16)y[r];
  ((bf16x4*)(outb + (size_t)row * Dx))[t] = yb;
}

extern "C" void kernel_launch(void* const* d_in, const int* in_sizes, int n_in,
                              void* d_out, int out_size, void* d_ws, size_t ws_size,
                              hipStream_t stream) {
  const int* tokens = (const int*)d_in[0];
  const float* emb = (const float*)d_in[1];
  const float* Wq = (const float*)d_in[2];
  const float* bq = (const float*)d_in[3];
  const float* Wk = (const float*)d_in[4];
  const float* bk = (const float*)d_in[5];
  const float* Wv = (const float*)d_in[6];
  const float* bv = (const float*)d_in[7];
  const float* Wo = (const float*)d_in[8];
  const float* bo = (const float*)d_in[9];
  const float* W1 = (const float*)d_in[10];
  const float* b1 = (const float*)d_in[11];
  const float* W2 = (const float*)d_in[12];
  const float* b2 = (const float*)d_in[13];
  const float* gamma = (const float*)d_in[14];
  const float* beta = (const float*)d_in[15];

  const size_t M1 = 1024 * 1024;
  float* ws = (float*)d_ws;
  float* x = ws;                        // 2M f32
  float* tmp = ws + 2 * M1;             // 2M f32 (split-K partial 0)
  __bf16* bfr = (__bf16*)(ws + 4 * M1);
  __bf16* xb = bfr;                     // 2M
  __bf16* qkvb = bfr + 2 * M1;          // 6M  [2048][3072] (V cols unused)
  __bf16* ob = bfr + 8 * M1;            // 2M
  __bf16* h1b = bfr + 10 * M1;          // 4M  [2048][2048]
  __bf16* Vt = bfr + 14 * M1;           // 2M  [B*H*64][S]
  __bf16* WqkvT = bfr + 16 * M1;        // 12M [L][3072][1024]
  __bf16* WoT = bfr + 28 * M1;          // 4M  [L][1024][1024]
  __bf16* W1T = bfr + 32 * M1;          // 8M  [L][2048][1024]
  __bf16* W2T = bfr + 40 * M1;          // 8M  [L][1024][2048]
  float* bqkv = (float*)(bfr + 48 * M1);  // [L][3072] f32
  float* tmp1 = (float*)qkvb;           // split-K partial 1 (qkvb free during Wo/FF2)

  embed_kernel<<<((size_t)Mx * Dx / 2 + 255) / 256, 256, 0, stream>>>(tokens, emb, x, xb);

  // batched weight prep for ALL layers (4 launches total)
  dim3 tb(32, 8);
  T4Args t4{Wq, Wk, Wv, Wo, WqkvT, WqkvT + M1, WqkvT + 2 * M1, WoT};
  transpose4_to_bf16<<<dim3(32, 32, 4 * Lx), tb, 0, stream>>>(t4);
  transpose_to_bf16<<<dim3(64, 32, Lx), tb, 0, stream>>>(W1, W1T, Dx, FFx, 2 * M1, 2 * M1);
  transpose_to_bf16<<<dim3(32, 64, Lx), tb, 0, stream>>>(W2, W2T, FFx, Dx, 2 * M1, 2 * M1);
  concat3_kernel<<<Lx * 12, 256, 0, stream>>>(bq, bk, bv, bqkv);

  for (int l = 0; l < Lx; ++l) {
    const __bf16* WqkvT_l = WqkvT + (size_t)l * 3 * M1;
    const __bf16* WoT_l = WoT + (size_t)l * M1;
    const __bf16* W1T_l = W1T + (size_t)l * 2 * M1;
    const __bf16* W2T_l = W2T + (size_t)l * 2 * M1;
    const float* bqkv_l = bqkv + (size_t)l * 3072;
    const float* bo_l = bo + (size_t)l * Dx;
    const float* b1_l = b1 + (size_t)l * FFx;
    const float* b2_l = b2 + (size_t)l * Dx;
    const float* g_l = gamma + (size_t)l * Dx;
    const float* be_l = beta + (size_t)l * Dx;

    // QKV: 128x64 tiles -> 768 blocks (3/CU); V blocks write transposed into Vt
    gemm_bt<128, 64, false, __bf16, true><<<dim3(3072 / 64, Mx / 128, 1), 256, 0, stream>>>(
        xb, WqkvT_l, bqkv_l, qkvb, nullptr, Vt, Dx, Dx, 3072);

    attention_mfma<<<dim3(Sx / 64, Hx, Bx), 256, 0, stream>>>(qkvb, Vt, ob);

    // Wo: 64x128 tiles, split-K=2 -> 512 blocks (2/CU); partials in tmp/tmp1
    gemm_bt<64, 128, false, float><<<dim3(Dx / 128, Mx / 64, 2), 256, 0, stream>>>(
        ob, WoT_l, bo_l, tmp, tmp1, nullptr, Dx / 2, Dx, Dx);
    add_ln_kernel<<<Mx, 256, 0, stream>>>(x, tmp, tmp1, g_l, be_l, x, xb);

    // FF1: 128x64 tiles -> 512 blocks (2/CU)
    gemm_bt<128, 64, true, __bf16><<<dim3(FFx / 64, Mx / 128, 1), 256, 0, stream>>>(
        xb, W1T_l, b1_l, h1b, nullptr, nullptr, Dx, Dx, FFx);
    // FF2: 64x128 tiles, split-K=2 -> 512 blocks
    gemm_bt<64, 128, false, float><<<dim3(Dx / 128, Mx / 64, 2), 256, 0, stream>>>(
        h1b, W2T_l, b2_l, tmp, tmp1, nullptr, FFx / 2, FFx, Dx);
    add_ln_kernel<<<Mx, 256, 0, stream>>>(x, tmp, tmp1, g_l, be_l,
                                          (l == Lx - 1) ? (float*)d_out : x, xb);
  }
}

// Round 3
// 748.992 us; speedup vs baseline: 1.0963x; 1.0591x over previous
//
#include <hip/hip_runtime.h>
#include <cstdint>
#include <cstddef>

#define Bx 2
#define Sx 1024
#define Dx 1024
#define Hx 16
#define Lx 4
#define FFx 2048
#define DKx 64
#define Mx (Bx * Sx)   // 2048 rows

typedef __attribute__((ext_vector_type(4))) float f32x4;
typedef __attribute__((ext_vector_type(8))) __bf16 bf16x8;
typedef __attribute__((ext_vector_type(4))) __bf16 bf16x4;
typedef __attribute__((ext_vector_type(2))) __bf16 bf16x2;

// ---------------- embed + positional encoding (pe indexed by BATCH, per ref bug) ----------------
__global__ void embed_kernel(const int* __restrict__ tokens,
                             const float* __restrict__ emb,
                             float* __restrict__ x, __bf16* __restrict__ xb) {
  size_t i = (size_t)blockIdx.x * blockDim.x + threadIdx.x;  // over Mx*Dx/2 pairs
  if (i >= (size_t)Mx * Dx / 2) return;
  int p = (int)(i % (Dx / 2));      // pair index within row
  size_t bs = i / (Dx / 2);
  int b = (int)(bs >> 10);          // batch index (Sx = 1024)
  int tok = tokens[bs];
  float arg = (float)b * expf((float)(2 * p) * (-logf(10000.0f) / (float)Dx));
  float sv, cv;
  __sincosf(arg, &sv, &cv);
  const float2 e = ((const float2*)(emb + (size_t)tok * Dx))[p];
  float2 o;
  o.x = e.x + sv;
  o.y = e.y + cv;
  ((float2*)x)[i] = o;
  bf16x2 ob;
  ob[0] = (__bf16)o.x;
  ob[1] = (__bf16)o.y;
  ((bf16x2*)xb)[i] = ob;
}

// ---------------- batched W[K,N] fp32 -> Wt[N,K] bf16 (32x32 tile transpose, z=layer) ----------------
__global__ void transpose_to_bf16(const float* __restrict__ W, __bf16* __restrict__ Wt,
                                  int K, int N, size_t sstride, size_t dstride) {
  __shared__ float tile[32][33];
  const float* Ws = W + blockIdx.z * sstride;
  __bf16* Wd = Wt + blockIdx.z * dstride;
  int tx = threadIdx.x, ty = threadIdx.y;  // 32 x 8
  int n0 = blockIdx.x * 32, k0 = blockIdx.y * 32;
#pragma unroll
  for (int i = 0; i < 4; ++i)
    tile[ty + 8 * i][tx] = Ws[(size_t)(k0 + ty + 8 * i) * N + n0 + tx];
  __syncthreads();
#pragma unroll
  for (int i = 0; i < 4; ++i)
    Wd[(size_t)(n0 + ty + 8 * i) * K + k0 + tx] = (__bf16)tile[tx][ty + 8 * i];
}

// 4 DxD weight transposes (Wq,Wk,Wv,Wo for all layers) in ONE launch: z = l*4 + which
struct T4Args {
  const float* s0; const float* s1; const float* s2; const float* s3;
  __bf16* d0; __bf16* d1; __bf16* d2; __bf16* d3;
};
__global__ void transpose4_to_bf16(T4Args a) {
  __shared__ float tile[32][33];
  const int zz = blockIdx.z, l = zz >> 2, which = zz & 3;
  const size_t M1c = (size_t)Dx * Dx;
  const float* Ws = (which == 0 ? a.s0 : which == 1 ? a.s1 : which == 2 ? a.s2 : a.s3) + (size_t)l * M1c;
  __bf16* Wd = (which == 0)   ? a.d0 + (size_t)l * 3 * M1c
               : (which == 1) ? a.d1 + (size_t)l * 3 * M1c
               : (which == 2) ? a.d2 + (size_t)l * 3 * M1c
                              : a.d3 + (size_t)l * M1c;
  int tx = threadIdx.x, ty = threadIdx.y;  // 32 x 8
  int n0 = blockIdx.x * 32, k0 = blockIdx.y * 32;
#pragma unroll
  for (int i = 0; i < 4; ++i)
    tile[ty + 8 * i][tx] = Ws[(size_t)(k0 + ty + 8 * i) * Dx + n0 + tx];
  __syncthreads();
#pragma unroll
  for (int i = 0; i < 4; ++i)
    Wd[(size_t)(n0 + ty + 8 * i) * Dx + k0 + tx] = (__bf16)tile[tx][ty + 8 * i];
}

// bias concat for all layers: bqkv[L][3072]
__global__ void concat3_kernel(const float* __restrict__ a, const float* __restrict__ b,
                               const float* __restrict__ c, float* __restrict__ out) {
  int i = blockIdx.x * 256 + threadIdx.x;  // over Lx*3072
  int l = i / 3072, j = i % 3072;
  float v = (j < 1024) ? a[l * 1024 + j]
                       : ((j < 2048) ? b[l * 1024 + j - 1024] : c[l * 1024 + j - 2048]);
  out[i] = v;
}

// XCD-aware bijective swizzle over flattened (x,y); requires nwg % 8 == 0
__device__ __forceinline__ void xcd_swz_xy(int& bx, int& by) {
  const int nwg = gridDim.x * gridDim.y;
  int flat = by * gridDim.x + bx;
  flat = (flat & 7) * (nwg >> 3) + (flat >> 3);
  bx = flat % gridDim.x;
  by = flat / gridDim.x;
}

// ---------------- bf16 MFMA GEMM: C = A[M,K] @ Bt[N,K]^T + bias ----------------
// TMxTN tile, BK=32, 4 waves, MI=2/NJ=4 each. 2-phase double-buffered LDS:
// per K-step {issue glds->buf^1; ds_read+MFMA from buf; __syncthreads (drains vmcnt)}.
// Load latency hides under the MFMA phase; one barrier per step.
// Optional split-K via gridDim.z (z=1 writes C1, bias only on z=0).
// VOUT: blocks with n0>=2048 are the V projection -> LDS-transpose the tile and
// write coalesced 64B segments into VT ([b*1024+dk][s] bf16).
__device__ __forceinline__ void gld_lds16(const void* g, void* l) {
  __builtin_amdgcn_global_load_lds(
      (const __attribute__((address_space(1))) void*)(uintptr_t)g,
      (__attribute__((address_space(3))) void*)(uintptr_t)l, 16, 0, 0);
}

template <int TM, int TN, bool RELU, typename OutT, bool VOUT = false>
__global__ __launch_bounds__(256) void gemm_bt(const __bf16* __restrict__ A,
                                               const __bf16* __restrict__ Bt,
                                               const float* __restrict__ bias,
                                               OutT* __restrict__ C0,
                                               float* __restrict__ C1,
                                               __bf16* __restrict__ VT,
                                               int Kstep, int Kld, int ldc) {
  static_assert((TM + TN) == 192, "NCH fixed at 12");
  static_assert(!VOUT || TN == 64, "VOUT path assumes TN=64/WC=0");
  __shared__ __align__(16) __bf16 lds[2][(TM + TN) * 32];  // 24 KB; VOUT reuses as 64x136
  const int t = threadIdx.x;
  const int w = t >> 6, lane = t & 63;
  const int quad = lane >> 4, l16 = lane & 15;
  int bx = blockIdx.x, by = blockIdx.y;
  xcd_swz_xy(bx, by);
  const int m0 = by * TM, n0 = bx * TN;
  const int lr = lane >> 2, lc = (lane & 3) * 8;  // staging: row-in-chunk, k-col
  const int koff = blockIdx.z * Kstep;

  f32x4 acc[2][4] = {};

  const int WR = (TN == 128) ? (w >> 1) * (TM / 2) : w * (TM / 4);
  const int WC = (TN == 128) ? (w & 1) * 64 : 0;
  const __bf16* Abase = A + (size_t)m0 * Kld + koff;
  const __bf16* Bbase = Bt + (size_t)n0 * Kld + koff;

  auto stage = [&](int buf, int k0) {
#pragma unroll
    for (int c = 0; c < 3; ++c) {
      const int ch = c * 4 + w;
      const int r = ch * 16 + lr;
      const __bf16* g = (r < TM) ? (Abase + (size_t)r * Kld + k0 + lc)
                                 : (Bbase + (size_t)(r - TM) * Kld + k0 + lc);
      gld_lds16(g, (void*)(&lds[buf][0] + ch * 512));
    }
  };

  // prologue: stage K-step 0 into buf 0
  stage(0, 0);
  __syncthreads();

  int cur = 0;
  for (int k0 = 0; k0 < Kstep; k0 += 32) {
    if (k0 + 32 < Kstep) stage(cur ^ 1, k0 + 32);  // issue-early: lands during MFMA below
    bf16x8 af[2], bfr[4];
#pragma unroll
    for (int i = 0; i < 2; ++i)
      af[i] = *(const bf16x8*)&lds[cur][(WR + i * 16 + l16) * 32 + quad * 8];
#pragma unroll
    for (int j = 0; j < 4; ++j)
      bfr[j] = *(const bf16x8*)&lds[cur][(TM + WC + j * 16 + l16) * 32 + quad * 8];
#pragma unroll
    for (int i = 0; i < 2; ++i)
#pragma unroll
      for (int j = 0; j < 4; ++j)
        acc[i][j] = __builtin_amdgcn_mfma_f32_16x16x32_bf16(af[i], bfr[j], acc[i][j], 0, 0, 0);
    __syncthreads();  // drains this step's glds (vmcnt 0) AFTER compute; guards buf reuse
    cur ^= 1;
  }

  // epilogue: C/D layout col=lane&15, row=(lane>>4)*4+reg (m89/m91-verified)
  const int col0 = n0 + WC + l16;

  if (VOUT && n0 >= 2048) {
    // V projection block: transpose through LDS, then coalesced stores into VT.
    __bf16* ldsf = &lds[0][0];  // 64 x 136 padded tile (17408 B <= 24 KB)
#pragma unroll
    for (int j = 0; j < 4; ++j) {
      const float bn = bias[col0 + j * 16];
      const int nl = (l16 + j * 16) * 136;
#pragma unroll
      for (int i = 0; i < 2; ++i)
#pragma unroll
        for (int r = 0; r < 4; ++r)
          ldsf[nl + WR + i * 16 + quad * 4 + r] = (__bf16)(acc[i][j][r] + bn);
    }
    __syncthreads();
    const int b = m0 >> 10;
    const int sbase = m0 & 1023;
    const int row = t >> 2, seg = t & 3;  // 64 rows x 4 segs of 64B
    __bf16* vrow = VT + (size_t)(b * 1024 + (n0 - 2048) + row) * Sx + sbase + seg * 32;
    const __bf16* lrow = ldsf + row * 136 + seg * 32;
#pragma unroll
    for (int q = 0; q < 4; ++q)
      *(bf16x8*)(vrow + q * 8) = *(const bf16x8*)(lrow + q * 8);
    return;
  }

  const bool z0 = (blockIdx.z == 0);
#pragma unroll
  for (int j = 0; j < 4; ++j) {
    const int n = col0 + j * 16;
    const float bn = z0 ? bias[n] : 0.f;
#pragma unroll
    for (int i = 0; i < 2; ++i) {
#pragma unroll
      for (int r = 0; r < 4; ++r) {
        const int m = m0 + WR + i * 16 + quad * 4 + r;
        float v = acc[i][j][r] + bn;
        if (RELU) v = fmaxf(v, 0.f);
        if (z0)
          C0[(size_t)m * ldc + n] = (OutT)v;
        else
          C1[(size_t)m * ldc + n] = v;
      }
    }
  }
}

// ---------------- MFMA flash attention: swapped QK^T, padded double-buffered LDS ----------------
// grid (S/64, H, B) XCD-swizzled, 256 threads (4 waves x 16 queries). One barrier
// per K-tile. QK^T computed as mfma(K,Q) so each lane holds
// P[q=w*16+l16][keys j*16+quad*4+r]: P->LDS is 4x ds_write_b64, l-sum scalar.
__global__ __launch_bounds__(256) void attention_mfma(const __bf16* __restrict__ QKV,
                                                      const __bf16* __restrict__ Vt,
                                                      __bf16* __restrict__ O) {
  __shared__ __align__(16) __bf16 Ks[2][64 * 72];  // [key][dk], stride 72
  __shared__ __align__(16) __bf16 Vs[2][64 * 72];  // [dk][key], stride 72
  __shared__ __align__(16) __bf16 Pl[64 * 72];     // wave-private rows: [q][key]

  const int t = threadIdx.x;
  const int w = t >> 6, lane = t & 63;
  const int quad = lane >> 4, l16 = lane & 15;
  int bx = blockIdx.x, by = blockIdx.y;
  xcd_swz_xy(bx, by);  // same-head blocks stay chunked on one XCD (K/V L2 reuse)
  const int q0 = bx * 64;
  const int h = by, b = blockIdx.z;
  const size_t rowbase = (size_t)b * Sx;
  const int hoff = h * 64;

  // Q fragments: rows q=w*16+l16, k=quad*8+e, in registers for the whole kernel
  const __bf16* qrow = QKV + (rowbase + q0 + w * 16 + l16) * 3072 + hoff;
  bf16x8 qf0 = *(const bf16x8*)(qrow + quad * 8);
  bf16x8 qf1 = *(const bf16x8*)(qrow + 32 + quad * 8);

  const __bf16* Kbase = QKV + rowbase * 3072 + 1024 + hoff;
  const __bf16* Vbase = Vt + (size_t)(b * Hx + h) * 64 * Sx;

  // staging role: thread t covers row srow, 32B segment sseg (coalesced 128B/4 lanes)
  const int srow = t >> 2, sseg = t & 3;
  bf16x8 kp0, kp1, vp0, vp1;

  f32x4 oacc[4] = {};
  float lsum = 0.f;
  const float cs = 0.125f * 1.44269504089f;  // fold 1/sqrt(64) and log2(e)

  // prologue: stage tile 0
  {
    const __bf16* kr = Kbase + (size_t)srow * 3072 + sseg * 16;
    kp0 = *(const bf16x8*)kr;
    kp1 = *(const bf16x8*)(kr + 8);
    const __bf16* vr = Vbase + (size_t)srow * Sx + sseg * 16;
    vp0 = *(const bf16x8*)vr;
    vp1 = *(const bf16x8*)(vr + 8);
    *(bf16x8*)&Ks[0][srow * 72 + sseg * 16] = kp0;
    *(bf16x8*)&Ks[0][srow * 72 + sseg * 16 + 8] = kp1;
    *(bf16x8*)&Vs[0][srow * 72 + sseg * 16] = vp0;
    *(bf16x8*)&Vs[0][srow * 72 + sseg * 16 + 8] = vp1;
  }
  __syncthreads();

  for (int kt = 0; kt < Sx / 64; ++kt) {
    const int cur = kt & 1;
    // prefetch next tile into regs (lands during this tile's compute)
    if (kt < Sx / 64 - 1) {
      const int kn = (kt + 1) * 64;
      const __bf16* kr = Kbase + (size_t)(kn + srow) * 3072 + sseg * 16;
      kp0 = *(const bf16x8*)kr;
      kp1 = *(const bf16x8*)(kr + 8);
      const __bf16* vr = Vbase + (size_t)srow * Sx + kn + sseg * 16;
      vp0 = *(const bf16x8*)vr;
      vp1 = *(const bf16x8*)(vr + 8);
    }

    // QK^T swapped: A=K-frag, B=Q-frag -> D[key][q]; lane holds q=w*16+l16,
    // keys j*16+quad*4+r
    f32x4 s[4] = {};
#pragma unroll
    for (int j = 0; j < 4; ++j) {
      bf16x8 b0 = *(const bf16x8*)&Ks[cur][(j * 16 + l16) * 72 + quad * 8];
      bf16x8 b1 = *(const bf16x8*)&Ks[cur][(j * 16 + l16) * 72 + 32 + quad * 8];
      s[j] = __builtin_amdgcn_mfma_f32_16x16x32_bf16(b0, qf0, s[j], 0, 0, 0);
      s[j] = __builtin_amdgcn_mfma_f32_16x16x32_bf16(b1, qf1, s[j], 0, 0, 0);
    }

    // p = exp2(s*cs); accumulate scalar row-sum (this lane's q only)
#pragma unroll
    for (int j = 0; j < 4; ++j) {
#pragma unroll
      for (int r = 0; r < 4; ++r) s[j][r] = __builtin_exp2f(s[j][r] * cs);
      lsum += s[j][0] + s[j][1] + s[j][2] + s[j][3];
    }

    // P -> wave-private LDS rows: 4x packed b64 (keys j*16+quad*4..+3)
    const int prow = (w * 16 + l16) * 72;
#pragma unroll
    for (int j = 0; j < 4; ++j) {
      bf16x4 pk;
#pragma unroll
      for (int r = 0; r < 4; ++r) pk[r] = (__bf16)s[j][r];
      *(bf16x4*)&Pl[prow + j * 16 + quad * 4] = pk;
    }
    bf16x8 pa0 = *(const bf16x8*)&Pl[prow + quad * 8];
    bf16x8 pa1 = *(const bf16x8*)&Pl[prow + 32 + quad * 8];

    // PV: B-fragments from padded LDS
#pragma unroll
    for (int j = 0; j < 4; ++j) {
      bf16x8 vb0 = *(const bf16x8*)&Vs[cur][(j * 16 + l16) * 72 + quad * 8];
      bf16x8 vb1 = *(const bf16x8*)&Vs[cur][(j * 16 + l16) * 72 + 32 + quad * 8];
      oacc[j] = __builtin_amdgcn_mfma_f32_16x16x32_bf16(pa0, vb0, oacc[j], 0, 0, 0);
      oacc[j] = __builtin_amdgcn_mfma_f32_16x16x32_bf16(pa1, vb1, oacc[j], 0, 0, 0);
    }

    // write prefetched tile into the other buffer (its readers synced last barrier)
    if (kt < Sx / 64 - 1) {
      const int nxt = 1 - cur;
      *(bf16x8*)&Ks[nxt][srow * 72 + sseg * 16] = kp0;
      *(bf16x8*)&Ks[nxt][srow * 72 + sseg * 16 + 8] = kp1;
      *(bf16x8*)&Vs[nxt][srow * 72 + sseg * 16] = vp0;
      *(bf16x8*)&Vs[nxt][srow * 72 + sseg * 16 + 8] = vp1;
    }
    __syncthreads();
  }

  // epilogue: lsum holds partial over this lane's quad; full sum = reduce over quads
  lsum += __shfl_xor(lsum, 16);
  lsum += __shfl_xor(lsum, 32);
  const float inv = 1.f / lsum;  // valid for q = w*16 + l16
#pragma unroll
  for (int r = 0; r < 4; ++r) {
    const float invr = __shfl(inv, quad * 4 + r);  // lane l16'=quad*4+r holds that q's inv
    const size_t orow = (rowbase + q0 + w * 16 + quad * 4 + r) * 1024 + hoff;
#pragma unroll
    for (int j = 0; j < 4; ++j) O[orow + j * 16 + l16] = (__bf16)(oacc[j][r] * invr);
  }
}

// ---------------- fused residual add (x + r0 + r1) + LayerNorm, dual fp32+bf16 out ----------------
__global__ void add_ln_kernel(const float* __restrict__ x, const float* __restrict__ r0,
                              const float* __restrict__ r1,
                              const float* __restrict__ gamma, const float* __restrict__ beta,
                              float* __restrict__ out, __bf16* __restrict__ outb) {
  const int row = blockIdx.x, t = threadIdx.x;
  const int lane = t & 63, w = t >> 6;
  __shared__ float red[2][4];
  const f32x4* xr = (const f32x4*)(x + (size_t)row * Dx);
  const f32x4* a0 = (const f32x4*)(r0 + (size_t)row * Dx);
  const f32x4* a1 = (const f32x4*)(r1 + (size_t)row * Dx);
  f32x4 v = xr[t] + a0[t] + a1[t];
  float s = v[0] + v[1] + v[2] + v[3];
#pragma unroll
  for (int off = 1; off < 64; off <<= 1) s += __shfl_xor(s, off);
  if (lane == 0) red[0][w] = s;
  __syncthreads();
  const float mu = (red[0][0] + red[0][1] + red[0][2] + red[0][3]) * (1.f / Dx);
  f32x4 d = v - mu;
  float vs = d[0] * d[0] + d[1] * d[1] + d[2] * d[2] + d[3] * d[3];
#pragma unroll
  for (int off = 1; off < 64; off <<= 1) vs += __shfl_xor(vs, off);
  if (lane == 0) red[1][w] = vs;
  __syncthreads();
  const float is = rsqrtf((red[1][0] + red[1][1] + red[1][2] + red[1][3]) * (1.f / Dx) + 1e-5f);
  f32x4 g = ((const f32x4*)gamma)[t];
  f32x4 be = ((const f32x4*)beta)[t];
  f32x4 y = d * is * g + be;
  ((f32x4*)(out + (size_t)row * Dx))[t] = y;
  bf16x4 yb;
#pragma unroll
  for (int r = 0; r < 4; ++r) yb[r] = (__bf16)y[r];
  ((bf16x4*)(outb + (size_t)row * Dx))[t] = yb;
}

extern "C" void kernel_launch(void* const* d_in, const int* in_sizes, int n_in,
                              void* d_out, int out_size, void* d_ws, size_t ws_size,
                              hipStream_t stream) {
  const int* tokens = (const int*)d_in[0];
  const float* emb = (const float*)d_in[1];
  const float* Wq = (const float*)d_in[2];
  const float* bq = (const float*)d_in[3];
  const float* Wk = (const float*)d_in[4];
  const float* bk = (const float*)d_in[5];
  const float* Wv = (const float*)d_in[6];
  const float* bv = (const float*)d_in[7];
  const float* Wo = (const float*)d_in[8];
  const float* bo = (const float*)d_in[9];
  const float* W1 = (const float*)d_in[10];
  const float* b1 = (const float*)d_in[11];
  const float* W2 = (const float*)d_in[12];
  const float* b2 = (const float*)d_in[13];
  const float* gamma = (const float*)d_in[14];
  const float* beta = (const float*)d_in[15];

  const size_t M1 = 1024 * 1024;
  float* ws = (float*)d_ws;
  float* x = ws;                        // 2M f32
  float* tmp = ws + 2 * M1;             // 2M f32 (split-K partial 0)
  __bf16* bfr = (__bf16*)(ws + 4 * M1);
  __bf16* xb = bfr;                     // 2M
  __bf16* qkvb = bfr + 2 * M1;          // 6M  [2048][3072] (V cols unused)
  __bf16* ob = bfr + 8 * M1;            // 2M
  __bf16* h1b = bfr + 10 * M1;          // 4M  [2048][2048]
  __bf16* Vt = bfr + 14 * M1;           // 2M  [B*H*64][S]
  __bf16* WqkvT = bfr + 16 * M1;        // 12M [L][3072][1024]
  __bf16* WoT = bfr + 28 * M1;          // 4M  [L][1024][1024]
  __bf16* W1T = bfr + 32 * M1;          // 8M  [L][2048][1024]
  __bf16* W2T = bfr + 40 * M1;          // 8M  [L][1024][2048]
  float* bqkv = (float*)(bfr + 48 * M1);  // [L][3072] f32
  float* tmp1 = (float*)qkvb;           // split-K partial 1 (qkvb free during Wo/FF2)

  embed_kernel<<<((size_t)Mx * Dx / 2 + 255) / 256, 256, 0, stream>>>(tokens, emb, x, xb);

  // batched weight prep for ALL layers (4 launches total)
  dim3 tb(32, 8);
  T4Args t4{Wq, Wk, Wv, Wo, WqkvT, WqkvT + M1, WqkvT + 2 * M1, WoT};
  transpose4_to_bf16<<<dim3(32, 32, 4 * Lx), tb, 0, stream>>>(t4);
  transpose_to_bf16<<<dim3(64, 32, Lx), tb, 0, stream>>>(W1, W1T, Dx, FFx, 2 * M1, 2 * M1);
  transpose_to_bf16<<<dim3(32, 64, Lx), tb, 0, stream>>>(W2, W2T, FFx, Dx, 2 * M1, 2 * M1);
  concat3_kernel<<<Lx * 12, 256, 0, stream>>>(bq, bk, bv, bqkv);

  for (int l = 0; l < Lx; ++l) {
    const __bf16* WqkvT_l = WqkvT + (size_t)l * 3 * M1;
    const __bf16* WoT_l = WoT + (size_t)l * M1;
    const __bf16* W1T_l = W1T + (size_t)l * 2 * M1;
    const __bf16* W2T_l = W2T + (size_t)l * 2 * M1;
    const float* bqkv_l = bqkv + (size_t)l * 3072;
    const float* bo_l = bo + (size_t)l * Dx;
    const float* b1_l = b1 + (size_t)l * FFx;
    const float* b2_l = b2 + (size_t)l * Dx;
    const float* g_l = gamma + (size_t)l * Dx;
    const float* be_l = beta + (size_t)l * Dx;

    // QKV: 128x64 tiles -> 768 blocks (3/CU); V blocks write transposed into Vt
    gemm_bt<128, 64, false, __bf16, true><<<dim3(3072 / 64, Mx / 128, 1), 256, 0, stream>>>(
        xb, WqkvT_l, bqkv_l, qkvb, nullptr, Vt, Dx, Dx, 3072);

    attention_mfma<<<dim3(Sx / 64, Hx, Bx), 256, 0, stream>>>(qkvb, Vt, ob);

    // Wo: 64x128 tiles, split-K=2 -> 512 blocks (2/CU); partials in tmp/tmp1
    gemm_bt<64, 128, false, float><<<dim3(Dx / 128, Mx / 64, 2), 256, 0, stream>>>(
        ob, WoT_l, bo_l, tmp, tmp1, nullptr, Dx / 2, Dx, Dx);
    add_ln_kernel<<<Mx, 256, 0, stream>>>(x, tmp, tmp1, g_l, be_l, x, xb);

    // FF1: 128x64 tiles -> 512 blocks (2/CU)
    gemm_bt<128, 64, true, __bf16><<<dim3(FFx / 64, Mx / 128, 1), 256, 0, stream>>>(
        xb, W1T_l, b1_l, h1b, nullptr, nullptr, Dx, Dx, FFx);
    // FF2: 64x128 tiles, split-K=2 -> 512 blocks
    gemm_bt<64, 128, false, float><<<dim3(Dx / 128, Mx / 64, 2), 256, 0, stream>>>(
        h1b, W2T_l, b2_l, tmp, tmp1, nullptr, FFx / 2, FFx, Dx);
    add_ln_kernel<<<Mx, 256, 0, stream>>>(x, tmp, tmp1, g_l, be_l,
                                          (l == Lx - 1) ? (float*)d_out : x, xb);
  }
}

// Round 4
// 731.183 us; speedup vs baseline: 1.1230x; 1.0244x over previous
//
#include <hip/hip_runtime.h>
#include <cstdint>
#include <cstddef>

#define Bx 2
#define Sx 1024
#define Dx 1024
#define Hx 16
#define Lx 4
#define FFx 2048
#define DKx 64
#define Mx (Bx * Sx)   // 2048 rows

typedef __attribute__((ext_vector_type(4))) float f32x4;
typedef __attribute__((ext_vector_type(8))) __bf16 bf16x8;
typedef __attribute__((ext_vector_type(4))) __bf16 bf16x4;
typedef __attribute__((ext_vector_type(2))) __bf16 bf16x2;

// ---------------- embed + positional encoding (pe indexed by BATCH, per ref bug) ----------------
__global__ void embed_kernel(const int* __restrict__ tokens,
                             const float* __restrict__ emb,
                             float* __restrict__ x, __bf16* __restrict__ xb) {
  size_t i = (size_t)blockIdx.x * blockDim.x + threadIdx.x;  // over Mx*Dx/2 pairs
  if (i >= (size_t)Mx * Dx / 2) return;
  int p = (int)(i % (Dx / 2));      // pair index within row
  size_t bs = i / (Dx / 2);
  int b = (int)(bs >> 10);          // batch index (Sx = 1024)
  int tok = tokens[bs];
  float arg = (float)b * expf((float)(2 * p) * (-logf(10000.0f) / (float)Dx));
  float sv, cv;
  __sincosf(arg, &sv, &cv);
  const float2 e = ((const float2*)(emb + (size_t)tok * Dx))[p];
  float2 o;
  o.x = e.x + sv;
  o.y = e.y + cv;
  ((float2*)x)[i] = o;
  bf16x2 ob;
  ob[0] = (__bf16)o.x;
  ob[1] = (__bf16)o.y;
  ((bf16x2*)xb)[i] = ob;
}

// ---------------- batched W[K,N] fp32 -> Wt[N,K] bf16 (32x32 tile transpose, z=layer) ----------------
__global__ void transpose_to_bf16(const float* __restrict__ W, __bf16* __restrict__ Wt,
                                  int K, int N, size_t sstride, size_t dstride) {
  __shared__ float tile[32][33];
  const float* Ws = W + blockIdx.z * sstride;
  __bf16* Wd = Wt + blockIdx.z * dstride;
  int tx = threadIdx.x, ty = threadIdx.y;  // 32 x 8
  int n0 = blockIdx.x * 32, k0 = blockIdx.y * 32;
#pragma unroll
  for (int i = 0; i < 4; ++i)
    tile[ty + 8 * i][tx] = Ws[(size_t)(k0 + ty + 8 * i) * N + n0 + tx];
  __syncthreads();
#pragma unroll
  for (int i = 0; i < 4; ++i)
    Wd[(size_t)(n0 + ty + 8 * i) * K + k0 + tx] = (__bf16)tile[tx][ty + 8 * i];
}

// 4 DxD weight transposes (Wq,Wk,Wv,Wo for all layers) in ONE launch: z = l*4 + which
struct T4Args {
  const float* s0; const float* s1; const float* s2; const float* s3;
  __bf16* d0; __bf16* d1; __bf16* d2; __bf16* d3;
};
__global__ void transpose4_to_bf16(T4Args a) {
  __shared__ float tile[32][33];
  const int zz = blockIdx.z, l = zz >> 2, which = zz & 3;
  const size_t M1c = (size_t)Dx * Dx;
  const float* Ws = (which == 0 ? a.s0 : which == 1 ? a.s1 : which == 2 ? a.s2 : a.s3) + (size_t)l * M1c;
  __bf16* Wd = (which == 0)   ? a.d0 + (size_t)l * 3 * M1c
               : (which == 1) ? a.d1 + (size_t)l * 3 * M1c
               : (which == 2) ? a.d2 + (size_t)l * 3 * M1c
                              : a.d3 + (size_t)l * M1c;
  int tx = threadIdx.x, ty = threadIdx.y;  // 32 x 8
  int n0 = blockIdx.x * 32, k0 = blockIdx.y * 32;
#pragma unroll
  for (int i = 0; i < 4; ++i)
    tile[ty + 8 * i][tx] = Ws[(size_t)(k0 + ty + 8 * i) * Dx + n0 + tx];
  __syncthreads();
#pragma unroll
  for (int i = 0; i < 4; ++i)
    Wd[(size_t)(n0 + ty + 8 * i) * Dx + k0 + tx] = (__bf16)tile[tx][ty + 8 * i];
}

// bias concat for all layers: bqkv[L][3072]
__global__ void concat3_kernel(const float* __restrict__ a, const float* __restrict__ b,
                               const float* __restrict__ c, float* __restrict__ out) {
  int i = blockIdx.x * 256 + threadIdx.x;  // over Lx*3072
  int l = i / 3072, j = i % 3072;
  float v = (j < 1024) ? a[l * 1024 + j]
                       : ((j < 2048) ? b[l * 1024 + j - 1024] : c[l * 1024 + j - 2048]);
  out[i] = v;
}

// XCD-aware bijective swizzle over flattened (x,y); requires nwg % 8 == 0
__device__ __forceinline__ void xcd_swz_xy(int& bx, int& by) {
  const int nwg = gridDim.x * gridDim.y;
  int flat = by * gridDim.x + bx;
  flat = (flat & 7) * (nwg >> 3) + (flat >> 3);
  bx = flat % gridDim.x;
  by = flat / gridDim.x;
}

// ---------------- bf16 MFMA GEMM: C = A[M,K] @ Bt[N,K]^T + bias ----------------
// TMxTN tile, BK=32, 4 waves, MI=2/NJ=4 each. 3-buffer counted-vmcnt pipeline (T4):
// per wave 2 stages (6 glds) in flight; per K-step wait only vmcnt(3) (the buffer
// about to be read) + lgkmcnt(0), raw s_barrier, then issue stage k+2. Loads span
// barriers; vmcnt never drains to 0 in the main loop.
// Optional split-K via gridDim.z (z=1 writes C1, bias only on z=0).
// VOUT: blocks with n0>=2048 are the V projection -> LDS-transpose the tile and
// write coalesced 64B segments into VT ([b*1024+dk][s] bf16).
__device__ __forceinline__ void gld_lds16(const void* g, void* l) {
  __builtin_amdgcn_global_load_lds(
      (const __attribute__((address_space(1))) void*)(uintptr_t)g,
      (__attribute__((address_space(3))) void*)(uintptr_t)l, 16, 0, 0);
}

template <int TM, int TN, bool RELU, typename OutT, bool VOUT = false>
__global__ __launch_bounds__(256) void gemm_bt(const __bf16* __restrict__ A,
                                               const __bf16* __restrict__ Bt,
                                               const float* __restrict__ bias,
                                               OutT* __restrict__ C0,
                                               float* __restrict__ C1,
                                               __bf16* __restrict__ VT,
                                               int Kstep, int Kld, int ldc) {
  static_assert((TM + TN) == 192, "NCH fixed at 12");
  static_assert(!VOUT || TN == 64, "VOUT path assumes TN=64/WC=0");
  __shared__ __align__(16) __bf16 lds[3][(TM + TN) * 32];  // 36 KB; VOUT reuses as 64x136
  const int t = threadIdx.x;
  const int w = t >> 6, lane = t & 63;
  const int quad = lane >> 4, l16 = lane & 15;
  int bx = blockIdx.x, by = blockIdx.y;
  xcd_swz_xy(bx, by);
  const int m0 = by * TM, n0 = bx * TN;
  const int lr = lane >> 2, lc = (lane & 3) * 8;  // staging: row-in-chunk, k-col
  const int koff = blockIdx.z * Kstep;

  f32x4 acc[2][4] = {};

  const int WR = (TN == 128) ? (w >> 1) * (TM / 2) : w * (TM / 4);
  const int WC = (TN == 128) ? (w & 1) * 64 : 0;
  const __bf16* Abase = A + (size_t)m0 * Kld + koff;
  const __bf16* Bbase = Bt + (size_t)n0 * Kld + koff;

  auto stage = [&](int buf, int k0) {
#pragma unroll
    for (int c = 0; c < 3; ++c) {
      const int ch = c * 4 + w;
      const int r = ch * 16 + lr;
      const __bf16* g = (r < TM) ? (Abase + (size_t)r * Kld + k0 + lc)
                                 : (Bbase + (size_t)(r - TM) * Kld + k0 + lc);
      gld_lds16(g, (void*)(&lds[buf][0] + ch * 512));
    }
  };

  // prologue: 2 stages in flight (6 glds/wave)
  stage(0, 0);
  stage(1, 32);

  int cur = 0;
  for (int k0 = 0; k0 < Kstep; k0 += 32) {
    // wait for buf[cur]'s loads only (oldest 3); keep newer stage in flight.
    // lgkmcnt(0): this wave's prior-iter ds_reads done before barrier -> the
    // buffer stage(k+2) overwrites (b(k-1)) is no longer being read by anyone.
    if (k0 + 32 < Kstep)
      asm volatile("s_waitcnt vmcnt(3) lgkmcnt(0)" ::: "memory");
    else
      asm volatile("s_waitcnt vmcnt(0) lgkmcnt(0)" ::: "memory");
    __builtin_amdgcn_s_barrier();
    __builtin_amdgcn_sched_barrier(0);  // pin ds_reads below the barrier (rule #18)

    int wb = cur + 2;
    if (wb >= 3) wb -= 3;
    if (k0 + 64 < Kstep) stage(wb, k0 + 64);  // issue-early; lands 2 iters later

    bf16x8 af[2], bfr[4];
#pragma unroll
    for (int i = 0; i < 2; ++i)
      af[i] = *(const bf16x8*)&lds[cur][(WR + i * 16 + l16) * 32 + quad * 8];
#pragma unroll
    for (int j = 0; j < 4; ++j)
      bfr[j] = *(const bf16x8*)&lds[cur][(TM + WC + j * 16 + l16) * 32 + quad * 8];
    __builtin_amdgcn_s_setprio(1);
#pragma unroll
    for (int i = 0; i < 2; ++i)
#pragma unroll
      for (int j = 0; j < 4; ++j)
        acc[i][j] = __builtin_amdgcn_mfma_f32_16x16x32_bf16(af[i], bfr[j], acc[i][j], 0, 0, 0);
    __builtin_amdgcn_s_setprio(0);
    cur = (cur + 1 == 3) ? 0 : cur + 1;
  }

  // epilogue: C/D layout col=lane&15, row=(lane>>4)*4+reg (m89/m91-verified)
  const int col0 = n0 + WC + l16;

  if (VOUT && n0 >= 2048) {
    // V projection block: transpose through LDS, then coalesced stores into VT.
    __syncthreads();  // loop has no trailing barrier; ensure all waves done with lds
    __bf16* ldsf = &lds[0][0];  // 64 x 136 padded tile (17408 B <= 36 KB)
#pragma unroll
    for (int j = 0; j < 4; ++j) {
      const float bn = bias[col0 + j * 16];
      const int nl = (l16 + j * 16) * 136;
#pragma unroll
      for (int i = 0; i < 2; ++i)
#pragma unroll
        for (int r = 0; r < 4; ++r)
          ldsf[nl + WR + i * 16 + quad * 4 + r] = (__bf16)(acc[i][j][r] + bn);
    }
    __syncthreads();
    const int b = m0 >> 10;
    const int sbase = m0 & 1023;
    const int row = t >> 2, seg = t & 3;  // 64 rows x 4 segs of 64B
    __bf16* vrow = VT + (size_t)(b * 1024 + (n0 - 2048) + row) * Sx + sbase + seg * 32;
    const __bf16* lrow = ldsf + row * 136 + seg * 32;
#pragma unroll
    for (int q = 0; q < 4; ++q)
      *(bf16x8*)(vrow + q * 8) = *(const bf16x8*)(lrow + q * 8);
    return;
  }

  const bool z0 = (blockIdx.z == 0);
#pragma unroll
  for (int j = 0; j < 4; ++j) {
    const int n = col0 + j * 16;
    const float bn = z0 ? bias[n] : 0.f;
#pragma unroll
    for (int i = 0; i < 2; ++i) {
#pragma unroll
      for (int r = 0; r < 4; ++r) {
        const int m = m0 + WR + i * 16 + quad * 4 + r;
        float v = acc[i][j][r] + bn;
        if (RELU) v = fmaxf(v, 0.f);
        if (z0)
          C0[(size_t)m * ldc + n] = (OutT)v;
        else
          C1[(size_t)m * ldc + n] = v;
      }
    }
  }
}

// ---------------- MFMA flash attention: swapped QK^T, padded double-buffered LDS ----------------
// grid (S/64, H, B) XCD-swizzled, 256 threads (4 waves x 16 queries). One barrier
// per K-tile. QK^T computed as mfma(K,Q) so each lane holds
// P[q=w*16+l16][keys j*16+quad*4+r]: P->LDS is 4x ds_write_b64, l-sum scalar.
__global__ __launch_bounds__(256) void attention_mfma(const __bf16* __restrict__ QKV,
                                                      const __bf16* __restrict__ Vt,
                                                      __bf16* __restrict__ O) {
  __shared__ __align__(16) __bf16 Ks[2][64 * 72];  // [key][dk], stride 72
  __shared__ __align__(16) __bf16 Vs[2][64 * 72];  // [dk][key], stride 72
  __shared__ __align__(16) __bf16 Pl[64 * 72];     // wave-private rows: [q][key]

  const int t = threadIdx.x;
  const int w = t >> 6, lane = t & 63;
  const int quad = lane >> 4, l16 = lane & 15;
  int bx = blockIdx.x, by = blockIdx.y;
  xcd_swz_xy(bx, by);  // same-head blocks stay chunked on one XCD (K/V L2 reuse)
  const int q0 = bx * 64;
  const int h = by, b = blockIdx.z;
  const size_t rowbase = (size_t)b * Sx;
  const int hoff = h * 64;

  // Q fragments: rows q=w*16+l16, k=quad*8+e, in registers for the whole kernel
  const __bf16* qrow = QKV + (rowbase + q0 + w * 16 + l16) * 3072 + hoff;
  bf16x8 qf0 = *(const bf16x8*)(qrow + quad * 8);
  bf16x8 qf1 = *(const bf16x8*)(qrow + 32 + quad * 8);

  const __bf16* Kbase = QKV + rowbase * 3072 + 1024 + hoff;
  const __bf16* Vbase = Vt + (size_t)(b * Hx + h) * 64 * Sx;

  // staging role: thread t covers row srow, 32B segment sseg (coalesced 128B/4 lanes)
  const int srow = t >> 2, sseg = t & 3;
  bf16x8 kp0, kp1, vp0, vp1;

  f32x4 oacc[4] = {};
  float lsum = 0.f;
  const float cs = 0.125f * 1.44269504089f;  // fold 1/sqrt(64) and log2(e)

  // prologue: stage tile 0
  {
    const __bf16* kr = Kbase + (size_t)srow * 3072 + sseg * 16;
    kp0 = *(const bf16x8*)kr;
    kp1 = *(const bf16x8*)(kr + 8);
    const __bf16* vr = Vbase + (size_t)srow * Sx + sseg * 16;
    vp0 = *(const bf16x8*)vr;
    vp1 = *(const bf16x8*)(vr + 8);
    *(bf16x8*)&Ks[0][srow * 72 + sseg * 16] = kp0;
    *(bf16x8*)&Ks[0][srow * 72 + sseg * 16 + 8] = kp1;
    *(bf16x8*)&Vs[0][srow * 72 + sseg * 16] = vp0;
    *(bf16x8*)&Vs[0][srow * 72 + sseg * 16 + 8] = vp1;
  }
  __syncthreads();

  for (int kt = 0; kt < Sx / 64; ++kt) {
    const int cur = kt & 1;
    // prefetch next tile into regs (lands during this tile's compute)
    if (kt < Sx / 64 - 1) {
      const int kn = (kt + 1) * 64;
      const __bf16* kr = Kbase + (size_t)(kn + srow) * 3072 + sseg * 16;
      kp0 = *(const bf16x8*)kr;
      kp1 = *(const bf16x8*)(kr + 8);
      const __bf16* vr = Vbase + (size_t)srow * Sx + kn + sseg * 16;
      vp0 = *(const bf16x8*)vr;
      vp1 = *(const bf16x8*)(vr + 8);
    }

    // QK^T swapped: A=K-frag, B=Q-frag -> D[key][q]; lane holds q=w*16+l16,
    // keys j*16+quad*4+r
    f32x4 s[4] = {};
#pragma unroll
    for (int j = 0; j < 4; ++j) {
      bf16x8 b0 = *(const bf16x8*)&Ks[cur][(j * 16 + l16) * 72 + quad * 8];
      bf16x8 b1 = *(const bf16x8*)&Ks[cur][(j * 16 + l16) * 72 + 32 + quad * 8];
      s[j] = __builtin_amdgcn_mfma_f32_16x16x32_bf16(b0, qf0, s[j], 0, 0, 0);
      s[j] = __builtin_amdgcn_mfma_f32_16x16x32_bf16(b1, qf1, s[j], 0, 0, 0);
    }

    // p = exp2(s*cs); accumulate scalar row-sum (this lane's q only)
#pragma unroll
    for (int j = 0; j < 4; ++j) {
#pragma unroll
      for (int r = 0; r < 4; ++r) s[j][r] = __builtin_exp2f(s[j][r] * cs);
      lsum += s[j][0] + s[j][1] + s[j][2] + s[j][3];
    }

    // P -> wave-private LDS rows: 4x packed b64 (keys j*16+quad*4..+3)
    const int prow = (w * 16 + l16) * 72;
#pragma unroll
    for (int j = 0; j < 4; ++j) {
      bf16x4 pk;
#pragma unroll
      for (int r = 0; r < 4; ++r) pk[r] = (__bf16)s[j][r];
      *(bf16x4*)&Pl[prow + j * 16 + quad * 4] = pk;
    }
    bf16x8 pa0 = *(const bf16x8*)&Pl[prow + quad * 8];
    bf16x8 pa1 = *(const bf16x8*)&Pl[prow + 32 + quad * 8];

    // PV: B-fragments from padded LDS
#pragma unroll
    for (int j = 0; j < 4; ++j) {
      bf16x8 vb0 = *(const bf16x8*)&Vs[cur][(j * 16 + l16) * 72 + quad * 8];
      bf16x8 vb1 = *(const bf16x8*)&Vs[cur][(j * 16 + l16) * 72 + 32 + quad * 8];
      oacc[j] = __builtin_amdgcn_mfma_f32_16x16x32_bf16(pa0, vb0, oacc[j], 0, 0, 0);
      oacc[j] = __builtin_amdgcn_mfma_f32_16x16x32_bf16(pa1, vb1, oacc[j], 0, 0, 0);
    }

    // write prefetched tile into the other buffer (its readers synced last barrier)
    if (kt < Sx / 64 - 1) {
      const int nxt = 1 - cur;
      *(bf16x8*)&Ks[nxt][srow * 72 + sseg * 16] = kp0;
      *(bf16x8*)&Ks[nxt][srow * 72 + sseg * 16 + 8] = kp1;
      *(bf16x8*)&Vs[nxt][srow * 72 + sseg * 16] = vp0;
      *(bf16x8*)&Vs[nxt][srow * 72 + sseg * 16 + 8] = vp1;
    }
    __syncthreads();
  }

  // epilogue: lsum holds partial over this lane's quad; full sum = reduce over quads
  lsum += __shfl_xor(lsum, 16);
  lsum += __shfl_xor(lsum, 32);
  const float inv = 1.f / lsum;  // valid for q = w*16 + l16
#pragma unroll
  for (int r = 0; r < 4; ++r) {
    const float invr = __shfl(inv, quad * 4 + r);  // lane l16'=quad*4+r holds that q's inv
    const size_t orow = (rowbase + q0 + w * 16 + quad * 4 + r) * 1024 + hoff;
#pragma unroll
    for (int j = 0; j < 4; ++j) O[orow + j * 16 + l16] = (__bf16)(oacc[j][r] * invr);
  }
}

// ---------------- fused residual add (x + r0 + r1) + LayerNorm, dual fp32+bf16 out ----------------
__global__ void add_ln_kernel(const float* __restrict__ x, const float* __restrict__ r0,
                              const float* __restrict__ r1,
                              const float* __restrict__ gamma, const float* __restrict__ beta,
                              float* __restrict__ out, __bf16* __restrict__ outb) {
  const int row = blockIdx.x, t = threadIdx.x;
  const int lane = t & 63, w = t >> 6;
  __shared__ float red[2][4];
  const f32x4* xr = (const f32x4*)(x + (size_t)row * Dx);
  const f32x4* a0 = (const f32x4*)(r0 + (size_t)row * Dx);
  const f32x4* a1 = (const f32x4*)(r1 + (size_t)row * Dx);
  f32x4 v = xr[t] + a0[t] + a1[t];
  float s = v[0] + v[1] + v[2] + v[3];
#pragma unroll
  for (int off = 1; off < 64; off <<= 1) s += __shfl_xor(s, off);
  if (lane == 0) red[0][w] = s;
  __syncthreads();
  const float mu = (red[0][0] + red[0][1] + red[0][2] + red[0][3]) * (1.f / Dx);
  f32x4 d = v - mu;
  float vs = d[0] * d[0] + d[1] * d[1] + d[2] * d[2] + d[3] * d[3];
#pragma unroll
  for (int off = 1; off < 64; off <<= 1) vs += __shfl_xor(vs, off);
  if (lane == 0) red[1][w] = vs;
  __syncthreads();
  const float is = rsqrtf((red[1][0] + red[1][1] + red[1][2] + red[1][3]) * (1.f / Dx) + 1e-5f);
  f32x4 g = ((const f32x4*)gamma)[t];
  f32x4 be = ((const f32x4*)beta)[t];
  f32x4 y = d * is * g + be;
  ((f32x4*)(out + (size_t)row * Dx))[t] = y;
  bf16x4 yb;
#pragma unroll
  for (int r = 0; r < 4; ++r) yb[r] = (__bf16)y[r];
  ((bf16x4*)(outb + (size_t)row * Dx))[t] = yb;
}

extern "C" void kernel_launch(void* const* d_in, const int* in_sizes, int n_in,
                              void* d_out, int out_size, void* d_ws, size_t ws_size,
                              hipStream_t stream) {
  const int* tokens = (const int*)d_in[0];
  const float* emb = (const float*)d_in[1];
  const float* Wq = (const float*)d_in[2];
  const float* bq = (const float*)d_in[3];
  const float* Wk = (const float*)d_in[4];
  const float* bk = (const float*)d_in[5];
  const float* Wv = (const float*)d_in[6];
  const float* bv = (const float*)d_in[7];
  const float* Wo = (const float*)d_in[8];
  const float* bo = (const float*)d_in[9];
  const float* W1 = (const float*)d_in[10];
  const float* b1 = (const float*)d_in[11];
  const float* W2 = (const float*)d_in[12];
  const float* b2 = (const float*)d_in[13];
  const float* gamma = (const float*)d_in[14];
  const float* beta = (const float*)d_in[15];

  const size_t M1 = 1024 * 1024;
  float* ws = (float*)d_ws;
  float* x = ws;                        // 2M f32
  float* tmp = ws + 2 * M1;             // 2M f32 (split-K partial 0)
  __bf16* bfr = (__bf16*)(ws + 4 * M1);
  __bf16* xb = bfr;                     // 2M
  __bf16* qkvb = bfr + 2 * M1;          // 6M  [2048][3072] (V cols unused)
  __bf16* ob = bfr + 8 * M1;            // 2M
  __bf16* h1b = bfr + 10 * M1;          // 4M  [2048][2048]
  __bf16* Vt = bfr + 14 * M1;           // 2M  [B*H*64][S]
  __bf16* WqkvT = bfr + 16 * M1;        // 12M [L][3072][1024]
  __bf16* WoT = bfr + 28 * M1;          // 4M  [L][1024][1024]
  __bf16* W1T = bfr + 32 * M1;          // 8M  [L][2048][1024]
  __bf16* W2T = bfr + 40 * M1;          // 8M  [L][1024][2048]
  float* bqkv = (float*)(bfr + 48 * M1);  // [L][3072] f32
  float* tmp1 = (float*)qkvb;           // split-K partial 1 (qkvb free during Wo/FF2)

  embed_kernel<<<((size_t)Mx * Dx / 2 + 255) / 256, 256, 0, stream>>>(tokens, emb, x, xb);

  // batched weight prep for ALL layers (4 launches total)
  dim3 tb(32, 8);
  T4Args t4{Wq, Wk, Wv, Wo, WqkvT, WqkvT + M1, WqkvT + 2 * M1, WoT};
  transpose4_to_bf16<<<dim3(32, 32, 4 * Lx), tb, 0, stream>>>(t4);
  transpose_to_bf16<<<dim3(64, 32, Lx), tb, 0, stream>>>(W1, W1T, Dx, FFx, 2 * M1, 2 * M1);
  transpose_to_bf16<<<dim3(32, 64, Lx), tb, 0, stream>>>(W2, W2T, FFx, Dx, 2 * M1, 2 * M1);
  concat3_kernel<<<Lx * 12, 256, 0, stream>>>(bq, bk, bv, bqkv);

  for (int l = 0; l < Lx; ++l) {
    const __bf16* WqkvT_l = WqkvT + (size_t)l * 3 * M1;
    const __bf16* WoT_l = WoT + (size_t)l * M1;
    const __bf16* W1T_l = W1T + (size_t)l * 2 * M1;
    const __bf16* W2T_l = W2T + (size_t)l * 2 * M1;
    const float* bqkv_l = bqkv + (size_t)l * 3072;
    const float* bo_l = bo + (size_t)l * Dx;
    const float* b1_l = b1 + (size_t)l * FFx;
    const float* b2_l = b2 + (size_t)l * Dx;
    const float* g_l = gamma + (size_t)l * Dx;
    const float* be_l = beta + (size_t)l * Dx;

    // QKV: 128x64 tiles -> 768 blocks (3/CU); V blocks write transposed into Vt
    gemm_bt<128, 64, false, __bf16, true><<<dim3(3072 / 64, Mx / 128, 1), 256, 0, stream>>>(
        xb, WqkvT_l, bqkv_l, qkvb, nullptr, Vt, Dx, Dx, 3072);

    attention_mfma<<<dim3(Sx / 64, Hx, Bx), 256, 0, stream>>>(qkvb, Vt, ob);

    // Wo: 64x128 tiles, split-K=2 -> 512 blocks (2/CU); partials in tmp/tmp1
    gemm_bt<64, 128, false, float><<<dim3(Dx / 128, Mx / 64, 2), 256, 0, stream>>>(
        ob, WoT_l, bo_l, tmp, tmp1, nullptr, Dx / 2, Dx, Dx);
    add_ln_kernel<<<Mx, 256, 0, stream>>>(x, tmp, tmp1, g_l, be_l, x, xb);

    // FF1: 128x64 tiles -> 512 blocks (2/CU)
    gemm_bt<128, 64, true, __bf16><<<dim3(FFx / 64, Mx / 128, 1), 256, 0, stream>>>(
        xb, W1T_l, b1_l, h1b, nullptr, nullptr, Dx, Dx, FFx);
    // FF2: 64x128 tiles, split-K=2 -> 512 blocks
    gemm_bt<64, 128, false, float><<<dim3(Dx / 128, Mx / 64, 2), 256, 0, stream>>>(
        h1b, W2T_l, b2_l, tmp, tmp1, nullptr, FFx / 2, FFx, Dx);
    add_ln_kernel<<<Mx, 256, 0, stream>>>(x, tmp, tmp1, g_l, be_l,
                                          (l == Lx - 1) ? (float*)d_out : x, xb);
  }
}

// Round 5
// 727.058 us; speedup vs baseline: 1.1294x; 1.0057x over previous
//
#include <hip/hip_runtime.h>
#include <cstdint>
#include <cstddef>

#define Bx 2
#define Sx 1024
#define Dx 1024
#define Hx 16
#define Lx 4
#define FFx 2048
#define DKx 64
#define Mx (Bx * Sx)   // 2048 rows

typedef __attribute__((ext_vector_type(4))) float f32x4;
typedef __attribute__((ext_vector_type(8))) __bf16 bf16x8;
typedef __attribute__((ext_vector_type(4))) __bf16 bf16x4;
typedef __attribute__((ext_vector_type(2))) __bf16 bf16x2;

// ---------------- embed + positional encoding (pe indexed by BATCH, per ref bug) ----------------
__global__ void embed_kernel(const int* __restrict__ tokens,
                             const float* __restrict__ emb,
                             float* __restrict__ x, __bf16* __restrict__ xb) {
  size_t i = (size_t)blockIdx.x * blockDim.x + threadIdx.x;  // over Mx*Dx/2 pairs
  if (i >= (size_t)Mx * Dx / 2) return;
  int p = (int)(i % (Dx / 2));      // pair index within row
  size_t bs = i / (Dx / 2);
  int b = (int)(bs >> 10);          // batch index (Sx = 1024)
  int tok = tokens[bs];
  float arg = (float)b * expf((float)(2 * p) * (-logf(10000.0f) / (float)Dx));
  float sv, cv;
  __sincosf(arg, &sv, &cv);
  const float2 e = ((const float2*)(emb + (size_t)tok * Dx))[p];
  float2 o;
  o.x = e.x + sv;
  o.y = e.y + cv;
  ((float2*)x)[i] = o;
  bf16x2 ob;
  ob[0] = (__bf16)o.x;
  ob[1] = (__bf16)o.y;
  ((bf16x2*)xb)[i] = ob;
}

// ---------------- batched W[K,N] fp32 -> Wt[N,K] bf16 (32x32 tile transpose, z=layer) ----------------
__global__ void transpose_to_bf16(const float* __restrict__ W, __bf16* __restrict__ Wt,
                                  int K, int N, size_t sstride, size_t dstride) {
  __shared__ float tile[32][33];
  const float* Ws = W + blockIdx.z * sstride;
  __bf16* Wd = Wt + blockIdx.z * dstride;
  int tx = threadIdx.x, ty = threadIdx.y;  // 32 x 8
  int n0 = blockIdx.x * 32, k0 = blockIdx.y * 32;
#pragma unroll
  for (int i = 0; i < 4; ++i)
    tile[ty + 8 * i][tx] = Ws[(size_t)(k0 + ty + 8 * i) * N + n0 + tx];
  __syncthreads();
#pragma unroll
  for (int i = 0; i < 4; ++i)
    Wd[(size_t)(n0 + ty + 8 * i) * K + k0 + tx] = (__bf16)tile[tx][ty + 8 * i];
}

// 4 DxD weight transposes (Wq,Wk,Wv,Wo for all layers) in ONE launch: z = l*4 + which
struct T4Args {
  const float* s0; const float* s1; const float* s2; const float* s3;
  __bf16* d0; __bf16* d1; __bf16* d2; __bf16* d3;
};
__global__ void transpose4_to_bf16(T4Args a) {
  __shared__ float tile[32][33];
  const int zz = blockIdx.z, l = zz >> 2, which = zz & 3;
  const size_t M1c = (size_t)Dx * Dx;
  const float* Ws = (which == 0 ? a.s0 : which == 1 ? a.s1 : which == 2 ? a.s2 : a.s3) + (size_t)l * M1c;
  __bf16* Wd = (which == 0)   ? a.d0 + (size_t)l * 3 * M1c
               : (which == 1) ? a.d1 + (size_t)l * 3 * M1c
               : (which == 2) ? a.d2 + (size_t)l * 3 * M1c
                              : a.d3 + (size_t)l * M1c;
  int tx = threadIdx.x, ty = threadIdx.y;  // 32 x 8
  int n0 = blockIdx.x * 32, k0 = blockIdx.y * 32;
#pragma unroll
  for (int i = 0; i < 4; ++i)
    tile[ty + 8 * i][tx] = Ws[(size_t)(k0 + ty + 8 * i) * Dx + n0 + tx];
  __syncthreads();
#pragma unroll
  for (int i = 0; i < 4; ++i)
    Wd[(size_t)(n0 + ty + 8 * i) * Dx + k0 + tx] = (__bf16)tile[tx][ty + 8 * i];
}

// bias concat for all layers: bqkv[L][3072]
__global__ void concat3_kernel(const float* __restrict__ a, const float* __restrict__ b,
                               const float* __restrict__ c, float* __restrict__ out) {
  int i = blockIdx.x * 256 + threadIdx.x;  // over Lx*3072
  int l = i / 3072, j = i % 3072;
  float v = (j < 1024) ? a[l * 1024 + j]
                       : ((j < 2048) ? b[l * 1024 + j - 1024] : c[l * 1024 + j - 2048]);
  out[i] = v;
}

// XCD-aware bijective swizzle over flattened (x,y); requires nwg % 8 == 0
__device__ __forceinline__ void xcd_swz_xy(int& bx, int& by) {
  const int nwg = gridDim.x * gridDim.y;
  int flat = by * gridDim.x + bx;
  flat = (flat & 7) * (nwg >> 3) + (flat >> 3);
  bx = flat % gridDim.x;
  by = flat / gridDim.x;
}

// ---------------- bf16 MFMA GEMM: C = A[M,K] @ Bt[N,K]^T + bias ----------------
// TMxTN tile, BK=32, 4 waves, MI=2/NJ=4 each. 3-buffer counted-vmcnt pipeline (T4):
// per wave 2 stages (6 glds) in flight; per K-step wait only vmcnt(3) (the buffer
// about to be read) + lgkmcnt(0), raw s_barrier, then issue stage k+2. Loads span
// barriers; vmcnt never drains to 0 in the main loop.
// Optional split-K via gridDim.z (z=1 writes C1, bias only on z=0).
// VOUT: blocks with n0>=2048 are the V projection -> LDS-transpose the tile and
// write coalesced 64B segments into VT ([b*1024+dk][s] bf16).
__device__ __forceinline__ void gld_lds16(const void* g, void* l) {
  __builtin_amdgcn_global_load_lds(
      (const __attribute__((address_space(1))) void*)(uintptr_t)g,
      (__attribute__((address_space(3))) void*)(uintptr_t)l, 16, 0, 0);
}

template <int TM, int TN, bool RELU, typename OutT, bool VOUT = false>
__global__ __launch_bounds__(256) void gemm_bt(const __bf16* __restrict__ A,
                                               const __bf16* __restrict__ Bt,
                                               const float* __restrict__ bias,
                                               OutT* __restrict__ C0,
                                               float* __restrict__ C1,
                                               __bf16* __restrict__ VT,
                                               int Kstep, int Kld, int ldc) {
  static_assert((TM + TN) == 192, "NCH fixed at 12");
  static_assert(!VOUT || TN == 64, "VOUT path assumes TN=64/WC=0");
  __shared__ __align__(16) __bf16 lds[3][(TM + TN) * 32];  // 36 KB; VOUT reuses as 64x136
  const int t = threadIdx.x;
  const int w = t >> 6, lane = t & 63;
  const int quad = lane >> 4, l16 = lane & 15;
  int bx = blockIdx.x, by = blockIdx.y;
  xcd_swz_xy(bx, by);
  const int m0 = by * TM, n0 = bx * TN;
  const int lr = lane >> 2, lc = (lane & 3) * 8;  // staging: row-in-chunk, k-col
  const int koff = blockIdx.z * Kstep;

  f32x4 acc[2][4] = {};

  const int WR = (TN == 128) ? (w >> 1) * (TM / 2) : w * (TM / 4);
  const int WC = (TN == 128) ? (w & 1) * 64 : 0;
  const __bf16* Abase = A + (size_t)m0 * Kld + koff;
  const __bf16* Bbase = Bt + (size_t)n0 * Kld + koff;

  auto stage = [&](int buf, int k0) {
#pragma unroll
    for (int c = 0; c < 3; ++c) {
      const int ch = c * 4 + w;
      const int r = ch * 16 + lr;
      const __bf16* g = (r < TM) ? (Abase + (size_t)r * Kld + k0 + lc)
                                 : (Bbase + (size_t)(r - TM) * Kld + k0 + lc);
      gld_lds16(g, (void*)(&lds[buf][0] + ch * 512));
    }
  };

  // prologue: 2 stages in flight (6 glds/wave)
  stage(0, 0);
  stage(1, 32);

  int cur = 0;
  for (int k0 = 0; k0 < Kstep; k0 += 32) {
    // wait for buf[cur]'s loads only (oldest 3); keep newer stage in flight.
    // lgkmcnt(0): this wave's prior-iter ds_reads done before barrier -> the
    // buffer stage(k+2) overwrites (b(k-1)) is no longer being read by anyone.
    if (k0 + 32 < Kstep)
      asm volatile("s_waitcnt vmcnt(3) lgkmcnt(0)" ::: "memory");
    else
      asm volatile("s_waitcnt vmcnt(0) lgkmcnt(0)" ::: "memory");
    __builtin_amdgcn_s_barrier();
    __builtin_amdgcn_sched_barrier(0);  // pin ds_reads below the barrier (rule #18)

    int wb = cur + 2;
    if (wb >= 3) wb -= 3;
    if (k0 + 64 < Kstep) stage(wb, k0 + 64);  // issue-early; lands 2 iters later

    bf16x8 af[2], bfr[4];
#pragma unroll
    for (int i = 0; i < 2; ++i)
      af[i] = *(const bf16x8*)&lds[cur][(WR + i * 16 + l16) * 32 + quad * 8];
#pragma unroll
    for (int j = 0; j < 4; ++j)
      bfr[j] = *(const bf16x8*)&lds[cur][(TM + WC + j * 16 + l16) * 32 + quad * 8];
    __builtin_amdgcn_s_setprio(1);
#pragma unroll
    for (int i = 0; i < 2; ++i)
#pragma unroll
      for (int j = 0; j < 4; ++j)
        acc[i][j] = __builtin_amdgcn_mfma_f32_16x16x32_bf16(af[i], bfr[j], acc[i][j], 0, 0, 0);
    __builtin_amdgcn_s_setprio(0);
    cur = (cur + 1 == 3) ? 0 : cur + 1;
  }

  // epilogue: C/D layout col=lane&15, row=(lane>>4)*4+reg (m89/m91-verified)
  const int col0 = n0 + WC + l16;

  if (VOUT && n0 >= 2048) {
    // V projection block: transpose through LDS, then coalesced stores into VT.
    __syncthreads();  // loop has no trailing barrier; ensure all waves done with lds
    __bf16* ldsf = &lds[0][0];  // 64 x 136 padded tile (17408 B <= 36 KB)
#pragma unroll
    for (int j = 0; j < 4; ++j) {
      const float bn = bias[col0 + j * 16];
      const int nl = (l16 + j * 16) * 136;
#pragma unroll
      for (int i = 0; i < 2; ++i)
#pragma unroll
        for (int r = 0; r < 4; ++r)
          ldsf[nl + WR + i * 16 + quad * 4 + r] = (__bf16)(acc[i][j][r] + bn);
    }
    __syncthreads();
    const int b = m0 >> 10;
    const int sbase = m0 & 1023;
    const int row = t >> 2, seg = t & 3;  // 64 rows x 4 segs of 64B
    __bf16* vrow = VT + (size_t)(b * 1024 + (n0 - 2048) + row) * Sx + sbase + seg * 32;
    const __bf16* lrow = ldsf + row * 136 + seg * 32;
#pragma unroll
    for (int q = 0; q < 4; ++q)
      *(bf16x8*)(vrow + q * 8) = *(const bf16x8*)(lrow + q * 8);
    return;
  }

  const bool z0 = (blockIdx.z == 0);
#pragma unroll
  for (int j = 0; j < 4; ++j) {
    const int n = col0 + j * 16;
    const float bn = z0 ? bias[n] : 0.f;
#pragma unroll
    for (int i = 0; i < 2; ++i) {
#pragma unroll
      for (int r = 0; r < 4; ++r) {
        const int m = m0 + WR + i * 16 + quad * 4 + r;
        float v = acc[i][j][r] + bn;
        if (RELU) v = fmaxf(v, 0.f);
        if (z0)
          C0[(size_t)m * ldc + n] = (OutT)v;
        else
          C1[(size_t)m * ldc + n] = v;
      }
    }
  }
}

// ---------------- MFMA flash attention: swapped QK^T, glds-direct XOR-swizzled LDS ----------------
// grid (S/64, H, B) XCD-swizzled, 256 threads (4 waves x 16 queries), 3 blocks/CU.
// K/V staged via global_load_lds into unpadded [64][64] tiles; T21 both-sides XOR
// swizzle (source colblk ^= row&7, linear dest, same XOR on B-frag reads) keeps
// ds_read_b128 at free 2-way bank aliasing. One barrier per K-tile; glds for kt+1
// issued before compute, drained (vmcnt 0) after compute.
// QK^T computed as mfma(K,Q) so each lane holds P[q=w*16+l16][keys j*16+quad*4+r]:
// P->LDS is 4x ds_write_b64, l-sum scalar.
__global__ __launch_bounds__(256, 3) void attention_mfma(const __bf16* __restrict__ QKV,
                                                         const __bf16* __restrict__ Vt,
                                                         __bf16* __restrict__ O) {
  __shared__ __align__(16) __bf16 Ks[2][64 * 64];  // [key][dk], swizzled
  __shared__ __align__(16) __bf16 Vs[2][64 * 64];  // [dk][key], swizzled
  __shared__ __align__(16) __bf16 Pl[64 * 72];     // wave-private rows: [q][key]

  const int t = threadIdx.x;
  const int w = t >> 6, lane = t & 63;
  const int quad = lane >> 4, l16 = lane & 15;
  int bx = blockIdx.x, by = blockIdx.y;
  xcd_swz_xy(bx, by);  // same-head blocks stay chunked on one XCD (K/V L2 reuse)
  const int q0 = bx * 64;
  const int h = by, b = blockIdx.z;
  const size_t rowbase = (size_t)b * Sx;
  const int hoff = h * 64;

  // Q fragments: rows q=w*16+l16, k=quad*8+e, in registers for the whole kernel
  const __bf16* qrow = QKV + (rowbase + q0 + w * 16 + l16) * 3072 + hoff;
  bf16x8 qf0 = *(const bf16x8*)(qrow + quad * 8);
  bf16x8 qf1 = *(const bf16x8*)(qrow + 32 + quad * 8);

  const __bf16* Kbase = QKV + rowbase * 3072 + 1024 + hoff;
  const __bf16* Vbase = Vt + (size_t)(b * Hx + h) * 64 * Sx;

  // glds staging: per wave 2 K-insts + 2 V-insts; each inst = 8 rows x 128B.
  // source colblk (16B units) = (lane&7) ^ (lane>>3)  [involution with row&7]
  const int lrow = lane >> 3;
  const int lcb = (lane & 7) ^ lrow;
  auto stageKV = [&](int buf, int kt64) {
#pragma unroll
    for (int c = 0; c < 2; ++c) {
      const int r8 = (c * 4 + w) * 8;
      gld_lds16(Kbase + (size_t)(kt64 + r8 + lrow) * 3072 + lcb * 8,
                (void*)&Ks[buf][(c * 4 + w) * 512]);
      gld_lds16(Vbase + (size_t)(r8 + lrow) * 1024 + kt64 + lcb * 8,
                (void*)&Vs[buf][(c * 4 + w) * 512]);
    }
  };

  f32x4 oacc[4] = {};
  float lsum = 0.f;
  const float cs = 0.125f * 1.44269504089f;  // fold 1/sqrt(64) and log2(e)

  // prologue: stage tile 0
  stageKV(0, 0);
  asm volatile("s_waitcnt vmcnt(0)" ::: "memory");
  __builtin_amdgcn_s_barrier();

  const int swz = l16 & 7;  // read-side row-XOR (matches source involution)
  for (int kt = 0; kt < Sx / 64; ++kt) {
    const int cur = kt & 1;
    // issue next tile's glds now; lands during this tile's compute
    if (kt < Sx / 64 - 1) stageKV(cur ^ 1, (kt + 1) * 64);

    // QK^T swapped: A=K-frag, B=Q-frag -> D[key][q]; lane holds q=w*16+l16,
    // keys j*16+quad*4+r
    f32x4 s[4] = {};
#pragma unroll
    for (int j = 0; j < 4; ++j) {
      bf16x8 b0 = *(const bf16x8*)&Ks[cur][(j * 16 + l16) * 64 + ((quad ^ swz) * 8)];
      bf16x8 b1 = *(const bf16x8*)&Ks[cur][(j * 16 + l16) * 64 + (((4 + quad) ^ swz) * 8)];
      __builtin_amdgcn_s_setprio(1);
      s[j] = __builtin_amdgcn_mfma_f32_16x16x32_bf16(b0, qf0, s[j], 0, 0, 0);
      s[j] = __builtin_amdgcn_mfma_f32_16x16x32_bf16(b1, qf1, s[j], 0, 0, 0);
      __builtin_amdgcn_s_setprio(0);
    }

    // p = exp2(s*cs); accumulate scalar row-sum (this lane's q only)
#pragma unroll
    for (int j = 0; j < 4; ++j) {
#pragma unroll
      for (int r = 0; r < 4; ++r) s[j][r] = __builtin_exp2f(s[j][r] * cs);
      lsum += s[j][0] + s[j][1] + s[j][2] + s[j][3];
    }

    // P -> wave-private LDS rows: 4x packed b64 (keys j*16+quad*4..+3)
    const int prow = (w * 16 + l16) * 72;
#pragma unroll
    for (int j = 0; j < 4; ++j) {
      bf16x4 pk;
#pragma unroll
      for (int r = 0; r < 4; ++r) pk[r] = (__bf16)s[j][r];
      *(bf16x4*)&Pl[prow + j * 16 + quad * 4] = pk;
    }
    bf16x8 pa0 = *(const bf16x8*)&Pl[prow + quad * 8];
    bf16x8 pa1 = *(const bf16x8*)&Pl[prow + 32 + quad * 8];

    // PV: B-fragments from swizzled LDS
#pragma unroll
    for (int j = 0; j < 4; ++j) {
      bf16x8 vb0 = *(const bf16x8*)&Vs[cur][(j * 16 + l16) * 64 + ((quad ^ swz) * 8)];
      bf16x8 vb1 = *(const bf16x8*)&Vs[cur][(j * 16 + l16) * 64 + (((4 + quad) ^ swz) * 8)];
      __builtin_amdgcn_s_setprio(1);
      oacc[j] = __builtin_amdgcn_mfma_f32_16x16x32_bf16(pa0, vb0, oacc[j], 0, 0, 0);
      oacc[j] = __builtin_amdgcn_mfma_f32_16x16x32_bf16(pa1, vb1, oacc[j], 0, 0, 0);
      __builtin_amdgcn_s_setprio(0);
    }

    // drain this iter's glds + all LDS reads, then release buffers
    asm volatile("s_waitcnt vmcnt(0) lgkmcnt(0)" ::: "memory");
    __builtin_amdgcn_s_barrier();
  }

  // epilogue: lsum holds partial over this lane's quad; full sum = reduce over quads
  lsum += __shfl_xor(lsum, 16);
  lsum += __shfl_xor(lsum, 32);
  const float inv = 1.f / lsum;  // valid for q = w*16 + l16
#pragma unroll
  for (int r = 0; r < 4; ++r) {
    const float invr = __shfl(inv, quad * 4 + r);  // lane l16'=quad*4+r holds that q's inv
    const size_t orow = (rowbase + q0 + w * 16 + quad * 4 + r) * 1024 + hoff;
#pragma unroll
    for (int j = 0; j < 4; ++j) O[orow + j * 16 + l16] = (__bf16)(oacc[j][r] * invr);
  }
}

// ---------------- fused residual add (x + r0 + r1) + LayerNorm, dual fp32+bf16 out ----------------
__global__ void add_ln_kernel(const float* __restrict__ x, const float* __restrict__ r0,
                              const float* __restrict__ r1,
                              const float* __restrict__ gamma, const float* __restrict__ beta,
                              float* __restrict__ out, __bf16* __restrict__ outb) {
  const int row = blockIdx.x, t = threadIdx.x;
  const int lane = t & 63, w = t >> 6;
  __shared__ float red[2][4];
  const f32x4* xr = (const f32x4*)(x + (size_t)row * Dx);
  const f32x4* a0 = (const f32x4*)(r0 + (size_t)row * Dx);
  const f32x4* a1 = (const f32x4*)(r1 + (size_t)row * Dx);
  f32x4 v = xr[t] + a0[t] + a1[t];
  float s = v[0] + v[1] + v[2] + v[3];
#pragma unroll
  for (int off = 1; off < 64; off <<= 1) s += __shfl_xor(s, off);
  if (lane == 0) red[0][w] = s;
  __syncthreads();
  const float mu = (red[0][0] + red[0][1] + red[0][2] + red[0][3]) * (1.f / Dx);
  f32x4 d = v - mu;
  float vs = d[0] * d[0] + d[1] * d[1] + d[2] * d[2] + d[3] * d[3];
#pragma unroll
  for (int off = 1; off < 64; off <<= 1) vs += __shfl_xor(vs, off);
  if (lane == 0) red[1][w] = vs;
  __syncthreads();
  const float is = rsqrtf((red[1][0] + red[1][1] + red[1][2] + red[1][3]) * (1.f / Dx) + 1e-5f);
  f32x4 g = ((const f32x4*)gamma)[t];
  f32x4 be = ((const f32x4*)beta)[t];
  f32x4 y = d * is * g + be;
  ((f32x4*)(out + (size_t)row * Dx))[t] = y;
  bf16x4 yb;
#pragma unroll
  for (int r = 0; r < 4; ++r) yb[r] = (__bf16)y[r];
  ((bf16x4*)(outb + (size_t)row * Dx))[t] = yb;
}

extern "C" void kernel_launch(void* const* d_in, const int* in_sizes, int n_in,
                              void* d_out, int out_size, void* d_ws, size_t ws_size,
                              hipStream_t stream) {
  const int* tokens = (const int*)d_in[0];
  const float* emb = (const float*)d_in[1];
  const float* Wq = (const float*)d_in[2];
  const float* bq = (const float*)d_in[3];
  const float* Wk = (const float*)d_in[4];
  const float* bk = (const float*)d_in[5];
  const float* Wv = (const float*)d_in[6];
  const float* bv = (const float*)d_in[7];
  const float* Wo = (const float*)d_in[8];
  const float* bo = (const float*)d_in[9];
  const float* W1 = (const float*)d_in[10];
  const float* b1 = (const float*)d_in[11];
  const float* W2 = (const float*)d_in[12];
  const float* b2 = (const float*)d_in[13];
  const float* gamma = (const float*)d_in[14];
  const float* beta = (const float*)d_in[15];

  const size_t M1 = 1024 * 1024;
  float* ws = (float*)d_ws;
  float* x = ws;                        // 2M f32
  float* tmp = ws + 2 * M1;             // 2M f32 (split-K partial 0)
  __bf16* bfr = (__bf16*)(ws + 4 * M1);
  __bf16* xb = bfr;                     // 2M
  __bf16* qkvb = bfr + 2 * M1;          // 6M  [2048][3072] (V cols unused)
  __bf16* ob = bfr + 8 * M1;            // 2M
  __bf16* h1b = bfr + 10 * M1;          // 4M  [2048][2048]
  __bf16* Vt = bfr + 14 * M1;           // 2M  [B*H*64][S]
  __bf16* WqkvT = bfr + 16 * M1;        // 12M [L][3072][1024]
  __bf16* WoT = bfr + 28 * M1;          // 4M  [L][1024][1024]
  __bf16* W1T = bfr + 32 * M1;          // 8M  [L][2048][1024]
  __bf16* W2T = bfr + 40 * M1;          // 8M  [L][1024][2048]
  float* bqkv = (float*)(bfr + 48 * M1);  // [L][3072] f32
  float* tmp1 = (float*)qkvb;           // split-K partial 1 (qkvb free during Wo/FF2)

  embed_kernel<<<((size_t)Mx * Dx / 2 + 255) / 256, 256, 0, stream>>>(tokens, emb, x, xb);

  // batched weight prep for ALL layers (4 launches total)
  dim3 tb(32, 8);
  T4Args t4{Wq, Wk, Wv, Wo, WqkvT, WqkvT + M1, WqkvT + 2 * M1, WoT};
  transpose4_to_bf16<<<dim3(32, 32, 4 * Lx), tb, 0, stream>>>(t4);
  transpose_to_bf16<<<dim3(64, 32, Lx), tb, 0, stream>>>(W1, W1T, Dx, FFx, 2 * M1, 2 * M1);
  transpose_to_bf16<<<dim3(32, 64, Lx), tb, 0, stream>>>(W2, W2T, FFx, Dx, 2 * M1, 2 * M1);
  concat3_kernel<<<Lx * 12, 256, 0, stream>>>(bq, bk, bv, bqkv);

  for (int l = 0; l < Lx; ++l) {
    const __bf16* WqkvT_l = WqkvT + (size_t)l * 3 * M1;
    const __bf16* WoT_l = WoT + (size_t)l * M1;
    const __bf16* W1T_l = W1T + (size_t)l * 2 * M1;
    const __bf16* W2T_l = W2T + (size_t)l * 2 * M1;
    const float* bqkv_l = bqkv + (size_t)l * 3072;
    const float* bo_l = bo + (size_t)l * Dx;
    const float* b1_l = b1 + (size_t)l * FFx;
    const float* b2_l = b2 + (size_t)l * Dx;
    const float* g_l = gamma + (size_t)l * Dx;
    const float* be_l = beta + (size_t)l * Dx;

    // QKV: 128x64 tiles -> 768 blocks (3/CU); V blocks write transposed into Vt
    gemm_bt<128, 64, false, __bf16, true><<<dim3(3072 / 64, Mx / 128, 1), 256, 0, stream>>>(
        xb, WqkvT_l, bqkv_l, qkvb, nullptr, Vt, Dx, Dx, 3072);

    attention_mfma<<<dim3(Sx / 64, Hx, Bx), 256, 0, stream>>>(qkvb, Vt, ob);

    // Wo: 64x128 tiles, split-K=2 -> 512 blocks (2/CU); partials in tmp/tmp1
    gemm_bt<64, 128, false, float><<<dim3(Dx / 128, Mx / 64, 2), 256, 0, stream>>>(
        ob, WoT_l, bo_l, tmp, tmp1, nullptr, Dx / 2, Dx, Dx);
    add_ln_kernel<<<Mx, 256, 0, stream>>>(x, tmp, tmp1, g_l, be_l, x, xb);

    // FF1: 128x64 tiles -> 512 blocks (2/CU)
    gemm_bt<128, 64, true, __bf16><<<dim3(FFx / 64, Mx / 128, 1), 256, 0, stream>>>(
        xb, W1T_l, b1_l, h1b, nullptr, nullptr, Dx, Dx, FFx);
    // FF2: 64x128 tiles, split-K=2 -> 512 blocks
    gemm_bt<64, 128, false, float><<<dim3(Dx / 128, Mx / 64, 2), 256, 0, stream>>>(
        h1b, W2T_l, b2_l, tmp, tmp1, nullptr, FFx / 2, FFx, Dx);
    add_ln_kernel<<<Mx, 256, 0, stream>>>(x, tmp, tmp1, g_l, be_l,
                                          (l == Lx - 1) ? (float*)d_out : x, xb);
  }
}

// Round 6
// 718.511 us; speedup vs baseline: 1.1428x; 1.0119x over previous
//
#include <hip/hip_runtime.h>
#include <cstdint>
#include <cstddef>

#define Bx 2
#define Sx 1024
#define Dx 1024
#define Hx 16
#define Lx 4
#define FFx 2048
#define DKx 64
#define Mx (Bx * Sx)   // 2048 rows

typedef __attribute__((ext_vector_type(4))) float f32x4;
typedef __attribute__((ext_vector_type(8))) __bf16 bf16x8;
typedef __attribute__((ext_vector_type(4))) __bf16 bf16x4;
typedef __attribute__((ext_vector_type(2))) __bf16 bf16x2;

// ---------------- embed + positional encoding (pe indexed by BATCH, per ref bug) ----------------
__global__ void embed_kernel(const int* __restrict__ tokens,
                             const float* __restrict__ emb,
                             float* __restrict__ x, __bf16* __restrict__ xb) {
  size_t i = (size_t)blockIdx.x * blockDim.x + threadIdx.x;  // over Mx*Dx/2 pairs
  if (i >= (size_t)Mx * Dx / 2) return;
  int p = (int)(i % (Dx / 2));      // pair index within row
  size_t bs = i / (Dx / 2);
  int b = (int)(bs >> 10);          // batch index (Sx = 1024)
  int tok = tokens[bs];
  float arg = (float)b * expf((float)(2 * p) * (-logf(10000.0f) / (float)Dx));
  float sv, cv;
  __sincosf(arg, &sv, &cv);
  const float2 e = ((const float2*)(emb + (size_t)tok * Dx))[p];
  float2 o;
  o.x = e.x + sv;
  o.y = e.y + cv;
  ((float2*)x)[i] = o;
  bf16x2 ob;
  ob[0] = (__bf16)o.x;
  ob[1] = (__bf16)o.y;
  ((bf16x2*)xb)[i] = ob;
}

// ---------------- batched W[K,N] fp32 -> Wt[N,K] bf16 (32x32 tile transpose, z=layer) ----------------
__global__ void transpose_to_bf16(const float* __restrict__ W, __bf16* __restrict__ Wt,
                                  int K, int N, size_t sstride, size_t dstride) {
  __shared__ float tile[32][33];
  const float* Ws = W + blockIdx.z * sstride;
  __bf16* Wd = Wt + blockIdx.z * dstride;
  int tx = threadIdx.x, ty = threadIdx.y;  // 32 x 8
  int n0 = blockIdx.x * 32, k0 = blockIdx.y * 32;
#pragma unroll
  for (int i = 0; i < 4; ++i)
    tile[ty + 8 * i][tx] = Ws[(size_t)(k0 + ty + 8 * i) * N + n0 + tx];
  __syncthreads();
#pragma unroll
  for (int i = 0; i < 4; ++i)
    Wd[(size_t)(n0 + ty + 8 * i) * K + k0 + tx] = (__bf16)tile[tx][ty + 8 * i];
}

// 4 DxD weight transposes (Wq,Wk,Wv,Wo for all layers) in ONE launch: z = l*4 + which
struct T4Args {
  const float* s0; const float* s1; const float* s2; const float* s3;
  __bf16* d0; __bf16* d1; __bf16* d2; __bf16* d3;
};
__global__ void transpose4_to_bf16(T4Args a) {
  __shared__ float tile[32][33];
  const int zz = blockIdx.z, l = zz >> 2, which = zz & 3;
  const size_t M1c = (size_t)Dx * Dx;
  const float* Ws = (which == 0 ? a.s0 : which == 1 ? a.s1 : which == 2 ? a.s2 : a.s3) + (size_t)l * M1c;
  __bf16* Wd = (which == 0)   ? a.d0 + (size_t)l * 3 * M1c
               : (which == 1) ? a.d1 + (size_t)l * 3 * M1c
               : (which == 2) ? a.d2 + (size_t)l * 3 * M1c
                              : a.d3 + (size_t)l * M1c;
  int tx = threadIdx.x, ty = threadIdx.y;  // 32 x 8
  int n0 = blockIdx.x * 32, k0 = blockIdx.y * 32;
#pragma unroll
  for (int i = 0; i < 4; ++i)
    tile[ty + 8 * i][tx] = Ws[(size_t)(k0 + ty + 8 * i) * Dx + n0 + tx];
  __syncthreads();
#pragma unroll
  for (int i = 0; i < 4; ++i)
    Wd[(size_t)(n0 + ty + 8 * i) * Dx + k0 + tx] = (__bf16)tile[tx][ty + 8 * i];
}

// bias concat for all layers: bqkv[L][3072]
__global__ void concat3_kernel(const float* __restrict__ a, const float* __restrict__ b,
                               const float* __restrict__ c, float* __restrict__ out) {
  int i = blockIdx.x * 256 + threadIdx.x;  // over Lx*3072
  int l = i / 3072, j = i % 3072;
  float v = (j < 1024) ? a[l * 1024 + j]
                       : ((j < 2048) ? b[l * 1024 + j - 1024] : c[l * 1024 + j - 2048]);
  out[i] = v;
}

// XCD-aware bijective swizzle over flattened (x,y); requires nwg % 8 == 0
__device__ __forceinline__ void xcd_swz_xy(int& bx, int& by) {
  const int nwg = gridDim.x * gridDim.y;
  int flat = by * gridDim.x + bx;
  flat = (flat & 7) * (nwg >> 3) + (flat >> 3);
  bx = flat % gridDim.x;
  by = flat / gridDim.x;
}

// ---------------- bf16 MFMA GEMM: C = A[M,K] @ Bt[N,K]^T + bias ----------------
// TMxTN tile, BK=32, WAVES waves (4 or 8); per wave MI=2/NJ=4 (8 MFMA/K-step).
// 3-buffer counted-vmcnt pipeline (T4): 2 stages (2*CPW glds) in flight per wave;
// per K-step wait vmcnt(CPW) (only the buffer about to be read) + lgkmcnt(0),
// raw s_barrier, then issue stage k+2. Loads span barriers; vmcnt never drains
// to 0 in the main loop. Optional split-K via gridDim.z (z=1 writes C1, bias z=0).
// VOUT (TN=64/WAVES=4 only): blocks with n0>=2048 are the V projection ->
// LDS-transpose the tile and write coalesced 64B segments into VT.
__device__ __forceinline__ void gld_lds16(const void* g, void* l) {
  __builtin_amdgcn_global_load_lds(
      (const __attribute__((address_space(1))) void*)(uintptr_t)g,
      (__attribute__((address_space(3))) void*)(uintptr_t)l, 16, 0, 0);
}

template <int TM, int TN, int WAVES, bool RELU, typename OutT, bool VOUT = false>
__global__ __launch_bounds__(WAVES * 64) void gemm_bt(const __bf16* __restrict__ A,
                                                      const __bf16* __restrict__ Bt,
                                                      const float* __restrict__ bias,
                                                      OutT* __restrict__ C0,
                                                      float* __restrict__ C1,
                                                      __bf16* __restrict__ VT,
                                                      int Kstep, int Kld, int ldc) {
  constexpr int NCH = (TM + TN) / 16;       // 16-row staging chunks
  constexpr int CPW = NCH / WAVES;          // chunks (glds) per wave per stage
  constexpr int NWC = TN / 64;              // wave-columns
  constexpr int NWR = WAVES / NWC;          // wave-rows
  static_assert(NCH % WAVES == 0 && TM / NWR == 32, "per-wave MI=2 layout");
  static_assert(!VOUT || (TN == 64 && WAVES == 4), "VOUT assumes TN=64/4-wave");
  __shared__ __align__(16) __bf16 lds[3][(TM + TN) * 32];
  const int t = threadIdx.x;
  const int w = t >> 6, lane = t & 63;
  const int quad = lane >> 4, l16 = lane & 15;
  int bx = blockIdx.x, by = blockIdx.y;
  xcd_swz_xy(bx, by);
  const int m0 = by * TM, n0 = bx * TN;
  const int lr = lane >> 2, lc = (lane & 3) * 8;  // staging: row-in-chunk, k-col
  const int koff = blockIdx.z * Kstep;

  f32x4 acc[2][4] = {};

  const int WR = (w % NWR) * 32;
  const int WC = (w / NWR) * 64;
  const __bf16* Abase = A + (size_t)m0 * Kld + koff;
  const __bf16* Bbase = Bt + (size_t)n0 * Kld + koff;

  auto stage = [&](int buf, int k0) {
#pragma unroll
    for (int c = 0; c < CPW; ++c) {
      const int ch = c * WAVES + w;
      const int r = ch * 16 + lr;
      const __bf16* g = (r < TM) ? (Abase + (size_t)r * Kld + k0 + lc)
                                 : (Bbase + (size_t)(r - TM) * Kld + k0 + lc);
      gld_lds16(g, (void*)(&lds[buf][0] + ch * 512));
    }
  };

  // prologue: 2 stages in flight (2*CPW glds/wave)
  stage(0, 0);
  stage(1, 32);

  int cur = 0;
  for (int k0 = 0; k0 < Kstep; k0 += 32) {
    // wait for buf[cur]'s loads only (oldest CPW); keep newer stage in flight.
    // lgkmcnt(0): prior-iter ds_reads done before barrier -> the buffer
    // stage(k+2) overwrites (b(k-1)) is no longer being read by anyone.
    if (k0 + 32 < Kstep) {
      if constexpr (CPW == 3)
        asm volatile("s_waitcnt vmcnt(3) lgkmcnt(0)" ::: "memory");
      else
        asm volatile("s_waitcnt vmcnt(2) lgkmcnt(0)" ::: "memory");
    } else {
      asm volatile("s_waitcnt vmcnt(0) lgkmcnt(0)" ::: "memory");
    }
    __builtin_amdgcn_s_barrier();
    __builtin_amdgcn_sched_barrier(0);  // pin ds_reads below the barrier (rule #18)

    int wb = cur + 2;
    if (wb >= 3) wb -= 3;
    if (k0 + 64 < Kstep) stage(wb, k0 + 64);  // issue-early; lands 2 iters later

    bf16x8 af[2], bfr[4];
#pragma unroll
    for (int i = 0; i < 2; ++i)
      af[i] = *(const bf16x8*)&lds[cur][(WR + i * 16 + l16) * 32 + quad * 8];
#pragma unroll
    for (int j = 0; j < 4; ++j)
      bfr[j] = *(const bf16x8*)&lds[cur][(TM + WC + j * 16 + l16) * 32 + quad * 8];
    __builtin_amdgcn_s_setprio(1);
#pragma unroll
    for (int i = 0; i < 2; ++i)
#pragma unroll
      for (int j = 0; j < 4; ++j)
        acc[i][j] = __builtin_amdgcn_mfma_f32_16x16x32_bf16(af[i], bfr[j], acc[i][j], 0, 0, 0);
    __builtin_amdgcn_s_setprio(0);
    cur = (cur + 1 == 3) ? 0 : cur + 1;
  }

  // epilogue: C/D layout col=lane&15, row=(lane>>4)*4+reg (m89/m91-verified)
  const int col0 = n0 + WC + l16;

  if (VOUT && n0 >= 2048) {
    // V projection block: transpose through LDS, then coalesced stores into VT.
    __syncthreads();  // loop has no trailing barrier; ensure all waves done with lds
    __bf16* ldsf = &lds[0][0];  // 64 x 136 padded tile (17408 B)
#pragma unroll
    for (int j = 0; j < 4; ++j) {
      const float bn = bias[col0 + j * 16];
      const int nl = (l16 + j * 16) * 136;
#pragma unroll
      for (int i = 0; i < 2; ++i)
#pragma unroll
        for (int r = 0; r < 4; ++r)
          ldsf[nl + WR + i * 16 + quad * 4 + r] = (__bf16)(acc[i][j][r] + bn);
    }
    __syncthreads();
    const int b = m0 >> 10;
    const int sbase = m0 & 1023;
    const int row = t >> 2, seg = t & 3;  // 64 rows x 4 segs of 64B
    __bf16* vrow = VT + (size_t)(b * 1024 + (n0 - 2048) + row) * Sx + sbase + seg * 32;
    const __bf16* lrow = ldsf + row * 136 + seg * 32;
#pragma unroll
    for (int q = 0; q < 4; ++q)
      *(bf16x8*)(vrow + q * 8) = *(const bf16x8*)(lrow + q * 8);
    return;
  }

  const bool z0 = (blockIdx.z == 0);
#pragma unroll
  for (int j = 0; j < 4; ++j) {
    const int n = col0 + j * 16;
    const float bn = z0 ? bias[n] : 0.f;
#pragma unroll
    for (int i = 0; i < 2; ++i) {
#pragma unroll
      for (int r = 0; r < 4; ++r) {
        const int m = m0 + WR + i * 16 + quad * 4 + r;
        float v = acc[i][j][r] + bn;
        if (RELU) v = fmaxf(v, 0.f);
        if (z0)
          C0[(size_t)m * ldc + n] = (OutT)v;
        else
          C1[(size_t)m * ldc + n] = v;
      }
    }
  }
}

// ---------------- MFMA flash attention: swapped QK^T, glds-direct XOR-swizzled LDS ----------------
// grid (S/64, H, B) XCD-swizzled, 256 threads (4 waves x 16 queries), 3 blocks/CU.
// K/V staged via global_load_lds into unpadded [64][64] tiles; T21 both-sides XOR
// swizzle (source colblk ^= row&7, linear dest, same XOR on B-frag reads).
__global__ __launch_bounds__(256, 3) void attention_mfma(const __bf16* __restrict__ QKV,
                                                         const __bf16* __restrict__ Vt,
                                                         __bf16* __restrict__ O) {
  __shared__ __align__(16) __bf16 Ks[2][64 * 64];  // [key][dk], swizzled
  __shared__ __align__(16) __bf16 Vs[2][64 * 64];  // [dk][key], swizzled
  __shared__ __align__(16) __bf16 Pl[64 * 72];     // wave-private rows: [q][key]

  const int t = threadIdx.x;
  const int w = t >> 6, lane = t & 63;
  const int quad = lane >> 4, l16 = lane & 15;
  int bx = blockIdx.x, by = blockIdx.y;
  xcd_swz_xy(bx, by);  // same-head blocks stay chunked on one XCD (K/V L2 reuse)
  const int q0 = bx * 64;
  const int h = by, b = blockIdx.z;
  const size_t rowbase = (size_t)b * Sx;
  const int hoff = h * 64;

  // Q fragments: rows q=w*16+l16, k=quad*8+e, in registers for the whole kernel
  const __bf16* qrow = QKV + (rowbase + q0 + w * 16 + l16) * 3072 + hoff;
  bf16x8 qf0 = *(const bf16x8*)(qrow + quad * 8);
  bf16x8 qf1 = *(const bf16x8*)(qrow + 32 + quad * 8);

  const __bf16* Kbase = QKV + rowbase * 3072 + 1024 + hoff;
  const __bf16* Vbase = Vt + (size_t)(b * Hx + h) * 64 * Sx;

  // glds staging: per wave 2 K-insts + 2 V-insts; each inst = 8 rows x 128B.
  // source colblk (16B units) = (lane&7) ^ (lane>>3)  [involution with row&7]
  const int lrow = lane >> 3;
  const int lcb = (lane & 7) ^ lrow;
  auto stageKV = [&](int buf, int kt64) {
#pragma unroll
    for (int c = 0; c < 2; ++c) {
      const int r8 = (c * 4 + w) * 8;
      gld_lds16(Kbase + (size_t)(kt64 + r8 + lrow) * 3072 + lcb * 8,
                (void*)&Ks[buf][(c * 4 + w) * 512]);
      gld_lds16(Vbase + (size_t)(r8 + lrow) * 1024 + kt64 + lcb * 8,
                (void*)&Vs[buf][(c * 4 + w) * 512]);
    }
  };

  f32x4 oacc[4] = {};
  float lsum = 0.f;
  const float cs = 0.125f * 1.44269504089f;  // fold 1/sqrt(64) and log2(e)

  // prologue: stage tile 0
  stageKV(0, 0);
  asm volatile("s_waitcnt vmcnt(0)" ::: "memory");
  __builtin_amdgcn_s_barrier();

  const int swz = l16 & 7;  // read-side row-XOR (matches source involution)
  for (int kt = 0; kt < Sx / 64; ++kt) {
    const int cur = kt & 1;
    // issue next tile's glds now; lands during this tile's compute
    if (kt < Sx / 64 - 1) stageKV(cur ^ 1, (kt + 1) * 64);

    // QK^T swapped: A=K-frag, B=Q-frag -> D[key][q]; lane holds q=w*16+l16,
    // keys j*16+quad*4+r
    f32x4 s[4] = {};
#pragma unroll
    for (int j = 0; j < 4; ++j) {
      bf16x8 b0 = *(const bf16x8*)&Ks[cur][(j * 16 + l16) * 64 + ((quad ^ swz) * 8)];
      bf16x8 b1 = *(const bf16x8*)&Ks[cur][(j * 16 + l16) * 64 + (((4 + quad) ^ swz) * 8)];
      __builtin_amdgcn_s_setprio(1);
      s[j] = __builtin_amdgcn_mfma_f32_16x16x32_bf16(b0, qf0, s[j], 0, 0, 0);
      s[j] = __builtin_amdgcn_mfma_f32_16x16x32_bf16(b1, qf1, s[j], 0, 0, 0);
      __builtin_amdgcn_s_setprio(0);
    }

    // p = exp2(s*cs); accumulate scalar row-sum (this lane's q only)
#pragma unroll
    for (int j = 0; j < 4; ++j) {
#pragma unroll
      for (int r = 0; r < 4; ++r) s[j][r] = __builtin_exp2f(s[j][r] * cs);
      lsum += s[j][0] + s[j][1] + s[j][2] + s[j][3];
    }

    // P -> wave-private LDS rows: 4x packed b64 (keys j*16+quad*4..+3)
    const int prow = (w * 16 + l16) * 72;
#pragma unroll
    for (int j = 0; j < 4; ++j) {
      bf16x4 pk;
#pragma unroll
      for (int r = 0; r < 4; ++r) pk[r] = (__bf16)s[j][r];
      *(bf16x4*)&Pl[prow + j * 16 + quad * 4] = pk;
    }
    bf16x8 pa0 = *(const bf16x8*)&Pl[prow + quad * 8];
    bf16x8 pa1 = *(const bf16x8*)&Pl[prow + 32 + quad * 8];

    // PV: B-fragments from swizzled LDS
#pragma unroll
    for (int j = 0; j < 4; ++j) {
      bf16x8 vb0 = *(const bf16x8*)&Vs[cur][(j * 16 + l16) * 64 + ((quad ^ swz) * 8)];
      bf16x8 vb1 = *(const bf16x8*)&Vs[cur][(j * 16 + l16) * 64 + (((4 + quad) ^ swz) * 8)];
      __builtin_amdgcn_s_setprio(1);
      oacc[j] = __builtin_amdgcn_mfma_f32_16x16x32_bf16(pa0, vb0, oacc[j], 0, 0, 0);
      oacc[j] = __builtin_amdgcn_mfma_f32_16x16x32_bf16(pa1, vb1, oacc[j], 0, 0, 0);
      __builtin_amdgcn_s_setprio(0);
    }

    // drain this iter's glds + all LDS reads, then release buffers
    asm volatile("s_waitcnt vmcnt(0) lgkmcnt(0)" ::: "memory");
    __builtin_amdgcn_s_barrier();
  }

  // epilogue: lsum holds partial over this lane's quad; full sum = reduce over quads
  lsum += __shfl_xor(lsum, 16);
  lsum += __shfl_xor(lsum, 32);
  const float inv = 1.f / lsum;  // valid for q = w*16 + l16
#pragma unroll
  for (int r = 0; r < 4; ++r) {
    const float invr = __shfl(inv, quad * 4 + r);  // lane l16'=quad*4+r holds that q's inv
    const size_t orow = (rowbase + q0 + w * 16 + quad * 4 + r) * 1024 + hoff;
#pragma unroll
    for (int j = 0; j < 4; ++j) O[orow + j * 16 + l16] = (__bf16)(oacc[j][r] * invr);
  }
}

// ---------------- fused residual add (x + r0 + r1) + LayerNorm, dual fp32+bf16 out ----------------
__global__ void add_ln_kernel(const float* __restrict__ x, const float* __restrict__ r0,
                              const float* __restrict__ r1,
                              const float* __restrict__ gamma, const float* __restrict__ beta,
                              float* __restrict__ out, __bf16* __restrict__ outb) {
  const int row = blockIdx.x, t = threadIdx.x;
  const int lane = t & 63, w = t >> 6;
  __shared__ float red[2][4];
  const f32x4* xr = (const f32x4*)(x + (size_t)row * Dx);
  const f32x4* a0 = (const f32x4*)(r0 + (size_t)row * Dx);
  const f32x4* a1 = (const f32x4*)(r1 + (size_t)row * Dx);
  f32x4 v = xr[t] + a0[t] + a1[t];
  float s = v[0] + v[1] + v[2] + v[3];
#pragma unroll
  for (int off = 1; off < 64; off <<= 1) s += __shfl_xor(s, off);
  if (lane == 0) red[0][w] = s;
  __syncthreads();
  const float mu = (red[0][0] + red[0][1] + red[0][2] + red[0][3]) * (1.f / Dx);
  f32x4 d = v - mu;
  float vs = d[0] * d[0] + d[1] * d[1] + d[2] * d[2] + d[3] * d[3];
#pragma unroll
  for (int off = 1; off < 64; off <<= 1) vs += __shfl_xor(vs, off);
  if (lane == 0) red[1][w] = vs;
  __syncthreads();
  const float is = rsqrtf((red[1][0] + red[1][1] + red[1][2] + red[1][3]) * (1.f / Dx) + 1e-5f);
  f32x4 g = ((const f32x4*)gamma)[t];
  f32x4 be = ((const f32x4*)beta)[t];
  f32x4 y = d * is * g + be;
  ((f32x4*)(out + (size_t)row * Dx))[t] = y;
  bf16x4 yb;
#pragma unroll
  for (int r = 0; r < 4; ++r) yb[r] = (__bf16)y[r];
  ((bf16x4*)(outb + (size_t)row * Dx))[t] = yb;
}

extern "C" void kernel_launch(void* const* d_in, const int* in_sizes, int n_in,
                              void* d_out, int out_size, void* d_ws, size_t ws_size,
                              hipStream_t stream) {
  const int* tokens = (const int*)d_in[0];
  const float* emb = (const float*)d_in[1];
  const float* Wq = (const float*)d_in[2];
  const float* bq = (const float*)d_in[3];
  const float* Wk = (const float*)d_in[4];
  const float* bk = (const float*)d_in[5];
  const float* Wv = (const float*)d_in[6];
  const float* bv = (const float*)d_in[7];
  const float* Wo = (const float*)d_in[8];
  const float* bo = (const float*)d_in[9];
  const float* W1 = (const float*)d_in[10];
  const float* b1 = (const float*)d_in[11];
  const float* W2 = (const float*)d_in[12];
  const float* b2 = (const float*)d_in[13];
  const float* gamma = (const float*)d_in[14];
  const float* beta = (const float*)d_in[15];

  const size_t M1 = 1024 * 1024;
  float* ws = (float*)d_ws;
  float* x = ws;                        // 2M f32
  float* tmp = ws + 2 * M1;             // 2M f32 (split-K partial 0)
  __bf16* bfr = (__bf16*)(ws + 4 * M1);
  __bf16* xb = bfr;                     // 2M
  __bf16* qkvb = bfr + 2 * M1;          // 6M  [2048][3072] (V cols unused)
  __bf16* ob = bfr + 8 * M1;            // 2M
  __bf16* h1b = bfr + 10 * M1;          // 4M  [2048][2048]
  __bf16* Vt = bfr + 14 * M1;           // 2M  [B*H*64][S]
  __bf16* WqkvT = bfr + 16 * M1;        // 12M [L][3072][1024]
  __bf16* WoT = bfr + 28 * M1;          // 4M  [L][1024][1024]
  __bf16* W1T = bfr + 32 * M1;          // 8M  [L][2048][1024]
  __bf16* W2T = bfr + 40 * M1;          // 8M  [L][1024][2048]
  float* bqkv = (float*)(bfr + 48 * M1);  // [L][3072] f32
  float* tmp1 = (float*)qkvb;           // split-K partial 1 (qkvb free during Wo/FF2)

  embed_kernel<<<((size_t)Mx * Dx / 2 + 255) / 256, 256, 0, stream>>>(tokens, emb, x, xb);

  // batched weight prep for ALL layers (4 launches total)
  dim3 tb(32, 8);
  T4Args t4{Wq, Wk, Wv, Wo, WqkvT, WqkvT + M1, WqkvT + 2 * M1, WoT};
  transpose4_to_bf16<<<dim3(32, 32, 4 * Lx), tb, 0, stream>>>(t4);
  transpose_to_bf16<<<dim3(64, 32, Lx), tb, 0, stream>>>(W1, W1T, Dx, FFx, 2 * M1, 2 * M1);
  transpose_to_bf16<<<dim3(32, 64, Lx), tb, 0, stream>>>(W2, W2T, FFx, Dx, 2 * M1, 2 * M1);
  concat3_kernel<<<Lx * 12, 256, 0, stream>>>(bq, bk, bv, bqkv);

  for (int l = 0; l < Lx; ++l) {
    const __bf16* WqkvT_l = WqkvT + (size_t)l * 3 * M1;
    const __bf16* WoT_l = WoT + (size_t)l * M1;
    const __bf16* W1T_l = W1T + (size_t)l * 2 * M1;
    const __bf16* W2T_l = W2T + (size_t)l * 2 * M1;
    const float* bqkv_l = bqkv + (size_t)l * 3072;
    const float* bo_l = bo + (size_t)l * Dx;
    const float* b1_l = b1 + (size_t)l * FFx;
    const float* b2_l = b2 + (size_t)l * Dx;
    const float* g_l = gamma + (size_t)l * Dx;
    const float* be_l = beta + (size_t)l * Dx;

    // QKV: 128x64 tiles, 4 waves -> 768 blocks (3/CU); V blocks write transposed into Vt
    gemm_bt<128, 64, 4, false, __bf16, true><<<dim3(3072 / 64, Mx / 128, 1), 256, 0, stream>>>(
        xb, WqkvT_l, bqkv_l, qkvb, nullptr, Vt, Dx, Dx, 3072);

    attention_mfma<<<dim3(Sx / 64, Hx, Bx), 256, 0, stream>>>(qkvb, Vt, ob);

    // Wo: 128x128 tiles, 8 waves, split-K=2 -> 256 blocks; partials in tmp/tmp1
    gemm_bt<128, 128, 8, false, float><<<dim3(Dx / 128, Mx / 128, 2), 512, 0, stream>>>(
        ob, WoT_l, bo_l, tmp, tmp1, nullptr, Dx / 2, Dx, Dx);
    add_ln_kernel<<<Mx, 256, 0, stream>>>(x, tmp, tmp1, g_l, be_l, x, xb);

    // FF1: 128x128 tiles, 8 waves -> 256 blocks (1/CU)
    gemm_bt<128, 128, 8, true, __bf16><<<dim3(FFx / 128, Mx / 128, 1), 512, 0, stream>>>(
        xb, W1T_l, b1_l, h1b, nullptr, nullptr, Dx, Dx, FFx);
    // FF2: 128x128 tiles, 8 waves, split-K=2 -> 256 blocks
    gemm_bt<128, 128, 8, false, float><<<dim3(Dx / 128, Mx / 128, 2), 512, 0, stream>>>(
        h1b, W2T_l, b2_l, tmp, tmp1, nullptr, FFx / 2, FFx, Dx);
    add_ln_kernel<<<Mx, 256, 0, stream>>>(x, tmp, tmp1, g_l, be_l,
                                          (l == Lx - 1) ? (float*)d_out : x, xb);
  }
}